// Round 1
// baseline (2123.906 us; speedup 1.0000x reference)
//
#include <hip/hip_runtime.h>
#include <hip/hip_bf16.h>
#include <cstdint>
#include <cmath>

// ResMoELoRALinear fused as ONE bf16 GEMM with augmented K:
//   out[8192,4096] = [x_bf16 | P] (8192x5120) @ [W_base | Bflat]^T (4096x5120) + b_base
// where P[t, n*64+r] = routing_w[t,n] * h[t,r] (top-2 sparse, rest zero),
//       Bflat[d, n*64+r] = B[n,d,r].
// Router/softmax/top-k computed in f32 to match reference expert selection.
// ws layout: Xa = 8192*5120 bf16 (83.9MB), Wa = 4096*5120 bf16 (41.9MB) -> 125.8MB total.

#define M_TOT 8192
#define N_OUT 4096
#define K_IN  4096
#define K_TOT 5120
#define NEXP  16
#define NRES  64

typedef __bf16 bf16x8 __attribute__((ext_vector_type(8)));
typedef float  f32x4  __attribute__((ext_vector_type(4)));
using u16 = unsigned short;

__device__ __forceinline__ u16 f2bf(float f) {
  union { float f; unsigned u; } v; v.f = f;
  unsigned u = v.u;
  return (u16)((u + 0x7FFFu + ((u >> 16) & 1u)) >> 16);   // RNE
}

__device__ __forceinline__ void gload_lds16(const void* g, void* l) {
  // global -> LDS direct DMA, 16B/lane. LDS dest must be wave-uniform;
  // HW adds lane*16. Casts via uintptr round-trip (generic LDS addr low32 = offset).
  const __attribute__((address_space(1))) unsigned* gp =
      (const __attribute__((address_space(1))) unsigned*)(unsigned long long)(uintptr_t)g;
  __attribute__((address_space(3))) unsigned* lp =
      (__attribute__((address_space(3))) unsigned*)(unsigned)(uintptr_t)l;
  __builtin_amdgcn_global_load_lds(gp, lp, 16, 0, 0);
}

// ---------------- Kernel 1: W_aug = [W_base | Bflat] as bf16 ----------------
__global__ __launch_bounds__(256) void build_waug(const float* __restrict__ Wb,
                                                  const float* __restrict__ Bm,
                                                  u16* __restrict__ Wa) {
  const int d = blockIdx.x;          // output feature row, 0..4095
  const int tid = threadIdx.x;
#pragma unroll
  for (int it = 0; it < 5; ++it) {
    int j = tid + it * 256;          // float4 index 0..1279
    int kcol = j * 4;
    float4 v;
    if (kcol < K_IN) {
      v = *(const float4*)(Wb + (size_t)d * K_IN + kcol);
    } else {
      int kk = kcol - K_IN;
      int n = kk >> 6, r = kk & 63;  // r%4==0 -> 16B aligned
      v = *(const float4*)(Bm + ((size_t)n * N_OUT + d) * NRES + r);
    }
    ushort4 o;
    o.x = f2bf(v.x); o.y = f2bf(v.y); o.z = f2bf(v.z); o.w = f2bf(v.w);
    *(ushort4*)(Wa + (size_t)d * K_TOT + kcol) = o;
  }
}

// ---- Kernel 2: per-token prep: x->bf16, router (f32), h (f32), P build ----
__global__ __launch_bounds__(256) void prep_tokens(const float* __restrict__ x,
                                                   const float* __restrict__ Wr,
                                                   const float* __restrict__ Amat,
                                                   const int* __restrict__ topk_p,
                                                   u16* __restrict__ Xa) {
  __shared__ float logits[16][16];
  __shared__ float hbuf[16][64];
  __shared__ float wexp[16][16];
  const int tid = threadIdx.x;
  const int w = tid >> 6, lane = tid & 63;
  const int token0 = blockIdx.x * 16;

  // Phase A: convert 16 x-rows to bf16 into Xa[:, 0:4096]
  for (int idx = tid; idx < 16 * 1024; idx += 256) {
    int t = idx >> 10, c4 = idx & 1023;
    const float4 v = *(const float4*)(x + (size_t)(token0 + t) * K_IN + c4 * 4);
    ushort4 o;
    o.x = f2bf(v.x); o.y = f2bf(v.y); o.z = f2bf(v.z); o.w = f2bf(v.w);
    *(ushort4*)(Xa + (size_t)(token0 + t) * K_TOT + c4 * 4) = o;
  }

  // Phase B: f32 dots. Each wave owns 4 tokens; per token 16 router + 64 hidden dots.
  for (int tt = 0; tt < 4; ++tt) {
    const int tl = w * 4 + tt;
    const float* xr = x + (size_t)(token0 + tl) * K_IN;
    for (int o = 0; o < 80; ++o) {
      const float* mr = (o < 16) ? (Wr + (size_t)o * K_IN)
                                 : (Amat + (size_t)(o - 16) * K_IN);
      float s0 = 0.f, s1 = 0.f, s2 = 0.f, s3 = 0.f;
      for (int i = lane; i < K_IN; i += 256) {
        s0 += xr[i]       * mr[i];
        s1 += xr[i + 64]  * mr[i + 64];
        s2 += xr[i + 128] * mr[i + 128];
        s3 += xr[i + 192] * mr[i + 192];
      }
      float s = (s0 + s1) + (s2 + s3);
      for (int off = 32; off > 0; off >>= 1) s += __shfl_xor(s, off, 64);
      if (lane == 0) {
        if (o < 16) logits[tl][o] = s;
        else        hbuf[tl][o - 16] = s;
      }
    }
  }
  __syncthreads();

  // Phase C: softmax + top-k + renorm (exactly reference: /(sum+1e-6))
  if (tid < 16) {
    const int t = tid;
    const int k = *topk_p;
    float p[16];
    float mx = logits[t][0];
#pragma unroll
    for (int e = 1; e < 16; ++e) mx = fmaxf(mx, logits[t][e]);
    float Z = 0.f;
#pragma unroll
    for (int e = 0; e < 16; ++e) { p[e] = expf(logits[t][e] - mx); Z += p[e]; }
    const float invZ = 1.f / Z;
#pragma unroll
    for (int e = 0; e < 16; ++e) p[e] *= invZ;
    float wv[16];
    if (k <= 0 || k >= NEXP) {
#pragma unroll
      for (int e = 0; e < 16; ++e) wv[e] = p[e];
    } else {
      unsigned um = 0; float ssum = 0.f;
      for (int kk = 0; kk < k; ++kk) {
        int best = 0; float bv = -1.f;
#pragma unroll
        for (int e = 0; e < 16; ++e)
          if (!((um >> e) & 1u) && p[e] > bv) { bv = p[e]; best = e; }
        um |= 1u << best; ssum += bv;
      }
      const float inv = 1.f / (ssum + 1e-6f);
#pragma unroll
      for (int e = 0; e < 16; ++e) wv[e] = ((um >> e) & 1u) ? p[e] * inv : 0.f;
    }
#pragma unroll
    for (int e = 0; e < 16; ++e) wexp[t][e] = wv[e];
  }
  __syncthreads();

  // Phase D: P write: Xa[t, 4096 + n*64 + r] = bf16(wexp[n] * h[r])
  for (int idx = tid; idx < 16 * 1024; idx += 256) {
    int t = idx >> 10, j = idx & 1023;
    int n = j >> 6, r = j & 63;
    float val = wexp[t][n] * hbuf[t][r];
    Xa[(size_t)(token0 + t) * K_TOT + K_IN + j] = f2bf(val);
  }
}

// ------ Kernel 3: m97-structure bf16 GEMM: C = Xa * Wa^T + bias (f32 out) ------
// BM=BN=128, BK=64, 256 thr = 4 waves (2x2), 4x4 frags of 16x16x32 per wave.
__global__ __launch_bounds__(256) void gemm_aug(const u16* __restrict__ Xa,
                                                const u16* __restrict__ Wa,
                                                const float* __restrict__ bias,
                                                float* __restrict__ out) {
  __shared__ __align__(16) u16 As[128 * 64];
  __shared__ __align__(16) u16 Bs[128 * 64];
  const int tid = threadIdx.x;
  const int w = tid >> 6, l = tid & 63;
  // XCD-bijective swizzle: 2048 wgs = 8 * 256
  const int bid = blockIdx.x;
  const int wg = (bid & 7) * 256 + (bid >> 3);
  const int bm = wg >> 5, bn = wg & 31;

  const int stRow = w * 8 + (l >> 3);            // 0..31 within a 32-row issue block
  const int stCol = (l & 7) * 8;                 // bf16 elems; *2B = lane*16B
  const u16* gA = Xa + (size_t)(bm * 128 + stRow) * K_TOT + stCol;
  const u16* gB = Wa + (size_t)(bn * 128 + stRow) * K_TOT + stCol;
  u16* lA = As + (size_t)(w * 8) * 64;           // wave-uniform LDS base
  u16* lB = Bs + (size_t)(w * 8) * 64;
  const int wr = w >> 1, wc = w & 1;

  f32x4 acc[4][4] = {};

  for (int kt = 0; kt < K_TOT / 64; ++kt) {
    const int k0 = kt * 64;
#pragma unroll
    for (int i = 0; i < 4; ++i) {
      gload_lds16(gA + (size_t)i * 32 * K_TOT + k0, lA + i * 32 * 64);
      gload_lds16(gB + (size_t)i * 32 * K_TOT + k0, lB + i * 32 * 64);
    }
    __syncthreads();   // drains vmcnt (global_load_lds) + lgkm
#pragma unroll
    for (int kk = 0; kk < 2; ++kk) {
      bf16x8 af[4], bfr[4];
#pragma unroll
      for (int m = 0; m < 4; ++m)
        af[m] = *(const bf16x8*)&As[(wr * 64 + m * 16 + (l & 15)) * 64 + kk * 32 + (l >> 4) * 8];
#pragma unroll
      for (int n = 0; n < 4; ++n)
        bfr[n] = *(const bf16x8*)&Bs[(wc * 64 + n * 16 + (l & 15)) * 64 + kk * 32 + (l >> 4) * 8];
#pragma unroll
      for (int m = 0; m < 4; ++m)
#pragma unroll
        for (int n = 0; n < 4; ++n)
          acc[m][n] = __builtin_amdgcn_mfma_f32_16x16x32_bf16(af[m], bfr[n], acc[m][n], 0, 0, 0);
    }
    __syncthreads();
  }

  // Epilogue: C/D layout col=lane&15, row=(lane>>4)*4+reg (m89-verified)
  float bv[4];
  const int colBase = bn * 128 + wc * 64 + (l & 15);
#pragma unroll
  for (int n = 0; n < 4; ++n) bv[n] = bias[colBase + n * 16];
#pragma unroll
  for (int m = 0; m < 4; ++m) {
    const int row = bm * 128 + wr * 64 + m * 16 + (l >> 4) * 4;
#pragma unroll
    for (int j = 0; j < 4; ++j) {
      float* orow = out + (size_t)(row + j) * N_OUT + colBase;
#pragma unroll
      for (int n = 0; n < 4; ++n) orow[n * 16] = acc[m][n][j] + bv[n];
    }
  }
}

extern "C" void kernel_launch(void* const* d_in, const int* in_sizes, int n_in,
                              void* d_out, int out_size, void* d_ws, size_t ws_size,
                              hipStream_t stream) {
  const float* x  = (const float*)d_in[0];
  const float* Wb = (const float*)d_in[1];
  const float* bb = (const float*)d_in[2];
  const float* Am = (const float*)d_in[3];
  const float* Bm = (const float*)d_in[4];
  const float* Wr = (const float*)d_in[5];
  const int* topk = (const int*)d_in[6];
  float* out = (float*)d_out;

  u16* Xa = (u16*)d_ws;                          // 8192*5120 bf16
  u16* Wa = Xa + (size_t)M_TOT * K_TOT;          // 4096*5120 bf16 (needs 125.8MB ws)

  hipLaunchKernelGGL(build_waug,  dim3(N_OUT),      dim3(256), 0, stream, Wb, Bm, Wa);
  hipLaunchKernelGGL(prep_tokens, dim3(M_TOT / 16), dim3(256), 0, stream, x, Wr, Am, topk, Xa);
  hipLaunchKernelGGL(gemm_aug,    dim3(2048),       dim3(256), 0, stream, Xa, Wa, bb, out);
}

// Round 2
// 717.828 us; speedup vs baseline: 2.9588x; 2.9588x over previous
//
#include <hip/hip_runtime.h>
#include <hip/hip_bf16.h>
#include <cstdint>
#include <cmath>

// ResMoELoRALinear fused as ONE bf16 GEMM with augmented K:
//   out[8192,4096] = [x_bf16 | P] (8192x5120) @ [W_base | Bflat]^T (4096x5120) + b_base
// where P[t, n*64+r] = routing_w[t,n] * h[t,r] (top-2 sparse, rest zero),
//       Bflat[d, n*64+r] = B[n,d,r].
// Router/softmax/top-k computed in f32 to match reference expert selection.
// ws layout: Xa = 8192*5120 bf16 (83.9MB), Wa = 4096*5120 bf16 (41.9MB).

#define M_TOT 8192
#define N_OUT 4096
#define K_IN  4096
#define K_TOT 5120
#define NEXP  16
#define NRES  64

typedef __bf16 bf16x8 __attribute__((ext_vector_type(8)));
typedef float  f32x4  __attribute__((ext_vector_type(4)));
using u16 = unsigned short;

__device__ __forceinline__ u16 f2bf(float f) {
  union { float f; unsigned u; } v; v.f = f;
  unsigned u = v.u;
  return (u16)((u + 0x7FFFu + ((u >> 16) & 1u)) >> 16);   // RNE
}

__device__ __forceinline__ void gload_lds16(const void* g, void* l) {
  const __attribute__((address_space(1))) unsigned* gp =
      (const __attribute__((address_space(1))) unsigned*)(unsigned long long)(uintptr_t)g;
  __attribute__((address_space(3))) unsigned* lp =
      (__attribute__((address_space(3))) unsigned*)(unsigned)(uintptr_t)l;
  __builtin_amdgcn_global_load_lds(gp, lp, 16, 0, 0);
}

// ---------------- Kernel 1: W_aug = [W_base | Bflat] as bf16 ----------------
__global__ __launch_bounds__(256) void build_waug(const float* __restrict__ Wb,
                                                  const float* __restrict__ Bm,
                                                  u16* __restrict__ Wa) {
  const int d = blockIdx.x;          // output feature row, 0..4095
  const int tid = threadIdx.x;
#pragma unroll
  for (int it = 0; it < 5; ++it) {
    int j = tid + it * 256;          // float4 index 0..1279
    int kcol = j * 4;
    float4 v;
    if (kcol < K_IN) {
      v = *(const float4*)(Wb + (size_t)d * K_IN + kcol);
    } else {
      int kk = kcol - K_IN;
      int n = kk >> 6, r = kk & 63;  // r%4==0 -> 16B aligned
      v = *(const float4*)(Bm + ((size_t)n * N_OUT + d) * NRES + r);
    }
    ushort4 o;
    o.x = f2bf(v.x); o.y = f2bf(v.y); o.z = f2bf(v.z); o.w = f2bf(v.w);
    *(ushort4*)(Wa + (size_t)d * K_TOT + kcol) = o;
  }
}

// ---- Kernel 2 (v2): tiled f32 mini-GEMM prep ----
// Per block: 16 tokens. H[t, 0..79] = x[t,:] . M[o,:] where M = [Wr(16); A(64)].
// K staged in 128-chunks in LDS; x->bf16 conversion fused into x staging.
// Thread (t = tid>>4, og = tid&15) owns token t, outputs og*5..og*5+4.
#define TM 16
#define KC 128
#define LP (KC + 4)   // LDS row stride in floats (pad 4 -> bank shift 4/row)

__global__ __launch_bounds__(256) void prep_tokens(const float* __restrict__ x,
                                                   const float* __restrict__ Wr,
                                                   const float* __restrict__ Amat,
                                                   const int* __restrict__ topk_p,
                                                   u16* __restrict__ Xa) {
  __shared__ __align__(16) float xs[TM][LP];
  __shared__ __align__(16) float Ms[80][LP];
  __shared__ float arr[TM][80];     // logits(0..15) + h(16..79)
  __shared__ float wexp[TM][16];

  const int tid = threadIdx.x;
  const int t  = tid >> 4;          // 0..15  (token slot)
  const int o0 = (tid & 15) * 5;    // output base, 0,5,...,75
  const int token0 = blockIdx.x * TM;

  float acc[5] = {0.f, 0.f, 0.f, 0.f, 0.f};

  for (int kc = 0; kc < K_IN / KC; ++kc) {
    const int k0 = kc * KC;
    // stage M chunk: 80 rows x 32 float4  (L2-resident source, 1.3 MB total)
#pragma unroll
    for (int it = 0; it < 10; ++it) {
      int idx = tid + it * 256;     // 0..2559
      int o = idx >> 5, kv = idx & 31;
      const float* src = (o < 16) ? (Wr + (size_t)o * K_IN)
                                  : (Amat + (size_t)(o - 16) * K_IN);
      *(float4*)&Ms[o][kv * 4] = *(const float4*)(src + k0 + kv * 4);
    }
    // stage x chunk + fused bf16 conversion: 16 rows x 32 float4
#pragma unroll
    for (int it = 0; it < 2; ++it) {
      int idx = tid + it * 256;     // 0..511
      int t2 = idx >> 5, kv = idx & 31;
      float4 v = *(const float4*)(x + (size_t)(token0 + t2) * K_IN + k0 + kv * 4);
      *(float4*)&xs[t2][kv * 4] = v;
      ushort4 o4;
      o4.x = f2bf(v.x); o4.y = f2bf(v.y); o4.z = f2bf(v.z); o4.w = f2bf(v.w);
      *(ushort4*)(Xa + (size_t)(token0 + t2) * K_TOT + k0 + kv * 4) = o4;
    }
    __syncthreads();
#pragma unroll
    for (int kv = 0; kv < 32; ++kv) {
      const float4 xv = *(const float4*)&xs[t][kv * 4];
#pragma unroll
      for (int oo = 0; oo < 5; ++oo) {
        const float4 mv = *(const float4*)&Ms[o0 + oo][kv * 4];
        acc[oo] += xv.x * mv.x + xv.y * mv.y + xv.z * mv.z + xv.w * mv.w;
      }
    }
    __syncthreads();
  }

#pragma unroll
  for (int oo = 0; oo < 5; ++oo) arr[t][o0 + oo] = acc[oo];
  __syncthreads();

  // softmax + top-k + renorm, f32, exactly reference semantics
  if (tid < TM) {
    const int tt = tid;
    const int k = *topk_p;
    float p[16];
    float mx = arr[tt][0];
#pragma unroll
    for (int e = 1; e < 16; ++e) mx = fmaxf(mx, arr[tt][e]);
    float Z = 0.f;
#pragma unroll
    for (int e = 0; e < 16; ++e) { p[e] = expf(arr[tt][e] - mx); Z += p[e]; }
    const float invZ = 1.f / Z;
#pragma unroll
    for (int e = 0; e < 16; ++e) p[e] *= invZ;
    float wv[16];
    if (k <= 0 || k >= NEXP) {
#pragma unroll
      for (int e = 0; e < 16; ++e) wv[e] = p[e];
    } else {
      unsigned um = 0; float ssum = 0.f;
      for (int kk = 0; kk < k; ++kk) {
        int best = 0; float bv = -1.f;
#pragma unroll
        for (int e = 0; e < 16; ++e)
          if (!((um >> e) & 1u) && p[e] > bv) { bv = p[e]; best = e; }
        um |= 1u << best; ssum += bv;
      }
      const float inv = 1.f / (ssum + 1e-6f);
#pragma unroll
      for (int e = 0; e < 16; ++e) wv[e] = ((um >> e) & 1u) ? p[e] * inv : 0.f;
    }
#pragma unroll
    for (int e = 0; e < 16; ++e) wexp[tt][e] = wv[e];
  }
  __syncthreads();

  // P write: Xa[t, 4096 + n*64 + r] = bf16(wexp[n] * h[r]); 16B per thread-iter
#pragma unroll
  for (int it = 0; it < 8; ++it) {
    int idx = tid + it * 256;       // 0..2047 over 16 tokens x 128 col-groups
    int tt = idx >> 7, c8 = idx & 127;
    int n = c8 >> 3, r0 = (c8 & 7) * 8;
    const float w = wexp[tt][n];
    ushort4 lo, hi;
    lo.x = f2bf(w * arr[tt][16 + r0 + 0]);
    lo.y = f2bf(w * arr[tt][16 + r0 + 1]);
    lo.z = f2bf(w * arr[tt][16 + r0 + 2]);
    lo.w = f2bf(w * arr[tt][16 + r0 + 3]);
    hi.x = f2bf(w * arr[tt][16 + r0 + 4]);
    hi.y = f2bf(w * arr[tt][16 + r0 + 5]);
    hi.z = f2bf(w * arr[tt][16 + r0 + 6]);
    hi.w = f2bf(w * arr[tt][16 + r0 + 7]);
    u16* dst = Xa + (size_t)(token0 + tt) * K_TOT + K_IN + c8 * 8;
    *(ushort4*)(dst) = lo;
    *(ushort4*)(dst + 4) = hi;
  }
}

// ------ Kernel 3: m97-structure bf16 GEMM: C = Xa * Wa^T + bias (f32 out) ------
// BM=BN=128, BK=64, 256 thr = 4 waves (2x2), 4x4 frags of 16x16x32 per wave.
__global__ __launch_bounds__(256) void gemm_aug(const u16* __restrict__ Xa,
                                                const u16* __restrict__ Wa,
                                                const float* __restrict__ bias,
                                                float* __restrict__ out) {
  __shared__ __align__(16) u16 As[128 * 64];
  __shared__ __align__(16) u16 Bs[128 * 64];
  const int tid = threadIdx.x;
  const int w = tid >> 6, l = tid & 63;
  // XCD-bijective swizzle: 2048 wgs = 8 * 256
  const int bid = blockIdx.x;
  const int wg = (bid & 7) * 256 + (bid >> 3);
  const int bm = wg >> 5, bn = wg & 31;

  const int stRow = w * 8 + (l >> 3);            // 0..31 within a 32-row issue block
  const int stCol = (l & 7) * 8;                 // bf16 elems; *2B = lane*16B
  const u16* gA = Xa + (size_t)(bm * 128 + stRow) * K_TOT + stCol;
  const u16* gB = Wa + (size_t)(bn * 128 + stRow) * K_TOT + stCol;
  u16* lA = As + (size_t)(w * 8) * 64;           // wave-uniform LDS base
  u16* lB = Bs + (size_t)(w * 8) * 64;
  const int wr = w >> 1, wc = w & 1;

  f32x4 acc[4][4] = {};

  for (int kt = 0; kt < K_TOT / 64; ++kt) {
    const int k0 = kt * 64;
#pragma unroll
    for (int i = 0; i < 4; ++i) {
      gload_lds16(gA + (size_t)i * 32 * K_TOT + k0, lA + i * 32 * 64);
      gload_lds16(gB + (size_t)i * 32 * K_TOT + k0, lB + i * 32 * 64);
    }
    __syncthreads();   // drains vmcnt (global_load_lds) + lgkm
#pragma unroll
    for (int kk = 0; kk < 2; ++kk) {
      bf16x8 af[4], bfr[4];
#pragma unroll
      for (int m = 0; m < 4; ++m)
        af[m] = *(const bf16x8*)&As[(wr * 64 + m * 16 + (l & 15)) * 64 + kk * 32 + (l >> 4) * 8];
#pragma unroll
      for (int n = 0; n < 4; ++n)
        bfr[n] = *(const bf16x8*)&Bs[(wc * 64 + n * 16 + (l & 15)) * 64 + kk * 32 + (l >> 4) * 8];
#pragma unroll
      for (int m = 0; m < 4; ++m)
#pragma unroll
        for (int n = 0; n < 4; ++n)
          acc[m][n] = __builtin_amdgcn_mfma_f32_16x16x32_bf16(af[m], bfr[n], acc[m][n], 0, 0, 0);
    }
    __syncthreads();
  }

  // Epilogue: C/D layout col=lane&15, row=(lane>>4)*4+reg (m89-verified)
  float bv[4];
  const int colBase = bn * 128 + wc * 64 + (l & 15);
#pragma unroll
  for (int n = 0; n < 4; ++n) bv[n] = bias[colBase + n * 16];
#pragma unroll
  for (int m = 0; m < 4; ++m) {
    const int row = bm * 128 + wr * 64 + m * 16 + (l >> 4) * 4;
#pragma unroll
    for (int j = 0; j < 4; ++j) {
      float* orow = out + (size_t)(row + j) * N_OUT + colBase;
#pragma unroll
      for (int n = 0; n < 4; ++n) orow[n * 16] = acc[m][n][j] + bv[n];
    }
  }
}

extern "C" void kernel_launch(void* const* d_in, const int* in_sizes, int n_in,
                              void* d_out, int out_size, void* d_ws, size_t ws_size,
                              hipStream_t stream) {
  const float* x  = (const float*)d_in[0];
  const float* Wb = (const float*)d_in[1];
  const float* bb = (const float*)d_in[2];
  const float* Am = (const float*)d_in[3];
  const float* Bm = (const float*)d_in[4];
  const float* Wr = (const float*)d_in[5];
  const int* topk = (const int*)d_in[6];
  float* out = (float*)d_out;

  u16* Xa = (u16*)d_ws;                          // 8192*5120 bf16
  u16* Wa = Xa + (size_t)M_TOT * K_TOT;          // 4096*5120 bf16

  hipLaunchKernelGGL(build_waug,  dim3(N_OUT),      dim3(256), 0, stream, Wb, Bm, Wa);
  hipLaunchKernelGGL(prep_tokens, dim3(M_TOT / TM), dim3(256), 0, stream, x, Wr, Am, topk, Xa);
  hipLaunchKernelGGL(gemm_aug,    dim3(2048),       dim3(256), 0, stream, Xa, Wa, bb, out);
}

// Round 3
// 559.416 us; speedup vs baseline: 3.7966x; 1.2832x over previous
//
#include <hip/hip_runtime.h>
#include <hip/hip_bf16.h>
#include <cstdint>
#include <cmath>

// ResMoELoRALinear fused as ONE bf16 GEMM with augmented K:
//   out[8192,4096] = [x_bf16 | P] (8192x5120) @ [W_base | Bflat]^T (4096x5120) + b_base
// GEMM is the 256^2 8-phase template (T1 XCD swizzle + T2 LDS XOR swizzle +
// T3/T4 counted-vmcnt pipeline + T5 setprio). prep/build unchanged from r2.

#define M_TOT 8192
#define N_OUT 4096
#define K_IN  4096
#define K_TOT 5120
#define NEXP  16
#define NRES  64
#define NT    (K_TOT / 64)   // 80 K-tiles

typedef __bf16 bf16x8 __attribute__((ext_vector_type(8)));
typedef float  f32x4  __attribute__((ext_vector_type(4)));
using u16 = unsigned short;

__device__ __forceinline__ u16 f2bf(float f) {
  union { float f; unsigned u; } v; v.f = f;
  unsigned u = v.u;
  return (u16)((u + 0x7FFFu + ((u >> 16) & 1u)) >> 16);   // RNE
}

__device__ __forceinline__ void gload_lds16(const void* g, void* l) {
  const __attribute__((address_space(1))) unsigned* gp =
      (const __attribute__((address_space(1))) unsigned*)(unsigned long long)(uintptr_t)g;
  __attribute__((address_space(3))) unsigned* lp =
      (__attribute__((address_space(3))) unsigned*)(unsigned)(uintptr_t)l;
  __builtin_amdgcn_global_load_lds(gp, lp, 16, 0, 0);
}

// ---------------- Kernel 1: W_aug = [W_base | Bflat] as bf16 ----------------
__global__ __launch_bounds__(256) void build_waug(const float* __restrict__ Wb,
                                                  const float* __restrict__ Bm,
                                                  u16* __restrict__ Wa) {
  const int d = blockIdx.x;
  const int tid = threadIdx.x;
#pragma unroll
  for (int it = 0; it < 5; ++it) {
    int j = tid + it * 256;
    int kcol = j * 4;
    float4 v;
    if (kcol < K_IN) {
      v = *(const float4*)(Wb + (size_t)d * K_IN + kcol);
    } else {
      int kk = kcol - K_IN;
      int n = kk >> 6, r = kk & 63;
      v = *(const float4*)(Bm + ((size_t)n * N_OUT + d) * NRES + r);
    }
    ushort4 o;
    o.x = f2bf(v.x); o.y = f2bf(v.y); o.z = f2bf(v.z); o.w = f2bf(v.w);
    *(ushort4*)(Wa + (size_t)d * K_TOT + kcol) = o;
  }
}

// ---- Kernel 2: tiled f32 mini-GEMM prep (unchanged from r2) ----
#define TM 16
#define KC 128
#define LP (KC + 4)

__global__ __launch_bounds__(256) void prep_tokens(const float* __restrict__ x,
                                                   const float* __restrict__ Wr,
                                                   const float* __restrict__ Amat,
                                                   const int* __restrict__ topk_p,
                                                   u16* __restrict__ Xa) {
  __shared__ __align__(16) float xs[TM][LP];
  __shared__ __align__(16) float Ms[80][LP];
  __shared__ float arr[TM][80];
  __shared__ float wexp[TM][16];

  const int tid = threadIdx.x;
  const int t  = tid >> 4;
  const int o0 = (tid & 15) * 5;
  const int token0 = blockIdx.x * TM;

  float acc[5] = {0.f, 0.f, 0.f, 0.f, 0.f};

  for (int kc = 0; kc < K_IN / KC; ++kc) {
    const int k0 = kc * KC;
#pragma unroll
    for (int it = 0; it < 10; ++it) {
      int idx = tid + it * 256;
      int o = idx >> 5, kv = idx & 31;
      const float* src = (o < 16) ? (Wr + (size_t)o * K_IN)
                                  : (Amat + (size_t)(o - 16) * K_IN);
      *(float4*)&Ms[o][kv * 4] = *(const float4*)(src + k0 + kv * 4);
    }
#pragma unroll
    for (int it = 0; it < 2; ++it) {
      int idx = tid + it * 256;
      int t2 = idx >> 5, kv = idx & 31;
      float4 v = *(const float4*)(x + (size_t)(token0 + t2) * K_IN + k0 + kv * 4);
      *(float4*)&xs[t2][kv * 4] = v;
      ushort4 o4;
      o4.x = f2bf(v.x); o4.y = f2bf(v.y); o4.z = f2bf(v.z); o4.w = f2bf(v.w);
      *(ushort4*)(Xa + (size_t)(token0 + t2) * K_TOT + k0 + kv * 4) = o4;
    }
    __syncthreads();
#pragma unroll
    for (int kv = 0; kv < 32; ++kv) {
      const float4 xv = *(const float4*)&xs[t][kv * 4];
#pragma unroll
      for (int oo = 0; oo < 5; ++oo) {
        const float4 mv = *(const float4*)&Ms[o0 + oo][kv * 4];
        acc[oo] += xv.x * mv.x + xv.y * mv.y + xv.z * mv.z + xv.w * mv.w;
      }
    }
    __syncthreads();
  }

#pragma unroll
  for (int oo = 0; oo < 5; ++oo) arr[t][o0 + oo] = acc[oo];
  __syncthreads();

  if (tid < TM) {
    const int tt = tid;
    const int k = *topk_p;
    float p[16];
    float mx = arr[tt][0];
#pragma unroll
    for (int e = 1; e < 16; ++e) mx = fmaxf(mx, arr[tt][e]);
    float Z = 0.f;
#pragma unroll
    for (int e = 0; e < 16; ++e) { p[e] = expf(arr[tt][e] - mx); Z += p[e]; }
    const float invZ = 1.f / Z;
#pragma unroll
    for (int e = 0; e < 16; ++e) p[e] *= invZ;
    float wv[16];
    if (k <= 0 || k >= NEXP) {
#pragma unroll
      for (int e = 0; e < 16; ++e) wv[e] = p[e];
    } else {
      unsigned um = 0; float ssum = 0.f;
      for (int kk = 0; kk < k; ++kk) {
        int best = 0; float bv = -1.f;
#pragma unroll
        for (int e = 0; e < 16; ++e)
          if (!((um >> e) & 1u) && p[e] > bv) { bv = p[e]; best = e; }
        um |= 1u << best; ssum += bv;
      }
      const float inv = 1.f / (ssum + 1e-6f);
#pragma unroll
      for (int e = 0; e < 16; ++e) wv[e] = ((um >> e) & 1u) ? p[e] * inv : 0.f;
    }
#pragma unroll
    for (int e = 0; e < 16; ++e) wexp[tt][e] = wv[e];
  }
  __syncthreads();

#pragma unroll
  for (int it = 0; it < 8; ++it) {
    int idx = tid + it * 256;
    int tt = idx >> 7, c8 = idx & 127;
    int n = c8 >> 3, r0 = (c8 & 7) * 8;
    const float w = wexp[tt][n];
    ushort4 lo, hi;
    lo.x = f2bf(w * arr[tt][16 + r0 + 0]);
    lo.y = f2bf(w * arr[tt][16 + r0 + 1]);
    lo.z = f2bf(w * arr[tt][16 + r0 + 2]);
    lo.w = f2bf(w * arr[tt][16 + r0 + 3]);
    hi.x = f2bf(w * arr[tt][16 + r0 + 4]);
    hi.y = f2bf(w * arr[tt][16 + r0 + 5]);
    hi.z = f2bf(w * arr[tt][16 + r0 + 6]);
    hi.w = f2bf(w * arr[tt][16 + r0 + 7]);
    u16* dst = Xa + (size_t)(token0 + tt) * K_TOT + K_IN + c8 * 8;
    *(ushort4*)(dst) = lo;
    *(ushort4*)(dst + 4) = hi;
  }
}

// ------ Kernel 3: 256^2 8-phase bf16 GEMM: C = Xa * Wa^T + bias ------
// 512 thr = 8 waves (2M x 4N); per-wave 128x64 out; BK=64; LDS 128 KiB dyn.
// LDS (u16 units): buf b: b*32768 ; A +0 / B +16384 ; half h: +h*8192 ; row: *64.
// T2 swizzle: stored granule g' = g ^ (row&7)  (granule = 8 u16 = 16B).

#define PHASE_BAR() do {                      \
  __builtin_amdgcn_sched_barrier(0);          \
  __builtin_amdgcn_s_barrier();               \
  __builtin_amdgcn_sched_barrier(0);          \
} while (0)

#define LGKM0() do {                          \
  asm volatile("s_waitcnt lgkmcnt(0)");       \
  __builtin_amdgcn_sched_barrier(0);          \
} while (0)

#define MFMA16 __builtin_amdgcn_mfma_f32_16x16x32_bf16

__global__ __launch_bounds__(512, 2) void gemm_aug(const u16* __restrict__ Xa,
                                                   const u16* __restrict__ Wa,
                                                   const float* __restrict__ bias,
                                                   float* __restrict__ out) {
  extern __shared__ u16 lds[];
  const int tid = threadIdx.x;
  const int w = tid >> 6, l = tid & 63;
  // T1: XCD-bijective chunked swizzle (512 wgs, 512%8==0, 64/XCD)
  const int bid = blockIdx.x;
  const int wg = (bid & 7) * 64 + (bid >> 3);
  const int bm = wg >> 4, bn = wg & 15;            // 32 x 16 tiles
  const int wm = w >> 2, wn = w & 3;

  // staging constants: row-in-qblock = w*8 + (l>>3); dest granule l&7;
  // source granule pre-swizzled: (l&7)^(l>>3)  [rule #21: linear dest + inv-swz src]
  const int srow = w * 8 + (l >> 3);
  const int gsw = ((l & 7) ^ (l >> 3)) * 8;
  const u16* sA = Xa + (size_t)(bm * 256 + srow) * K_TOT + gsw;
  const u16* sB = Wa + (size_t)(bn * 256 + srow) * K_TOT + gsw;
  const int stq = w * 512;                          // wave-uniform dest off (u16)

  // fragment-read constants (T2 swizzle on read: g' = g ^ (l&7); row&7 == l&7)
  const int arow = (l & 15) * 64;
  const int c0 = (((l >> 4) + 0) ^ (l & 7)) * 8;
  const int c1 = (((l >> 4) + 4) ^ (l & 7)) * 8;

  f32x4 acc[8][4] = {};

  // ---- prologue: issue (0).B0,B1,A0,A1, (1).B0,B1,A0 ; vmcnt(6) ; barrier ----
#define STAGE_A(tile, half) do {                                               \
    const u16* s_ = sA + (size_t)(half) * 128 * K_TOT + (size_t)(tile) * 64;   \
    const int d_ = ((tile) & 1) * 32768 + (half) * 8192 + stq;                 \
    gload_lds16(s_, &lds[d_]);                                                 \
    gload_lds16(s_ + (size_t)64 * K_TOT, &lds[d_ + 4096]);                     \
  } while (0)
#define STAGE_B(tile, half) do {                                               \
    const u16* s_ = sB + (size_t)(half) * 128 * K_TOT + (size_t)(tile) * 64;   \
    const int d_ = ((tile) & 1) * 32768 + 16384 + (half) * 8192 + stq;         \
    gload_lds16(s_, &lds[d_]);                                                 \
    gload_lds16(s_ + (size_t)64 * K_TOT, &lds[d_ + 4096]);                     \
  } while (0)

  STAGE_B(0, 0); STAGE_B(0, 1); STAGE_A(0, 0); STAGE_A(0, 1);
  STAGE_B(1, 0); STAGE_B(1, 1); STAGE_A(1, 0);
  __builtin_amdgcn_sched_barrier(0);
  asm volatile("s_waitcnt vmcnt(6)");
  PHASE_BAR();

  for (int t = 0; t < NT; ++t) {
    const int bufOff = (t & 1) * 32768;
    const int aoff = bufOff + wm * 8192;
    const int boff = bufOff + 16384 + (wn >> 1) * 8192 + (wn & 1) * 4096;
    bf16x8 af[4][2], b0f[2][2], b1f[2][2];

    // ---- P1: read A[mh0] + B[nh0]; stage (t+1).A1; mfma quadrant (0,0) ----
#pragma unroll
    for (int m = 0; m < 4; ++m) {
      af[m][0] = *(const bf16x8*)&lds[aoff + m * 1024 + arow + c0];
      af[m][1] = *(const bf16x8*)&lds[aoff + m * 1024 + arow + c1];
    }
#pragma unroll
    for (int n = 0; n < 2; ++n) {
      b0f[n][0] = *(const bf16x8*)&lds[boff + n * 1024 + arow + c0];
      b0f[n][1] = *(const bf16x8*)&lds[boff + n * 1024 + arow + c1];
    }
    if (t + 1 < NT) STAGE_A(t + 1, 1);
    PHASE_BAR(); LGKM0();
    __builtin_amdgcn_s_setprio(1);
#pragma unroll
    for (int m = 0; m < 4; ++m)
#pragma unroll
      for (int n = 0; n < 2; ++n) {
        acc[m][n] = MFMA16(af[m][0], b0f[n][0], acc[m][n], 0, 0, 0);
        acc[m][n] = MFMA16(af[m][1], b0f[n][1], acc[m][n], 0, 0, 0);
      }
    __builtin_amdgcn_s_setprio(0);
    PHASE_BAR();

    // ---- P2: read B[nh1]; stage (t+2).B0; mfma quadrant (0,1) ----
#pragma unroll
    for (int n = 0; n < 2; ++n) {
      b1f[n][0] = *(const bf16x8*)&lds[boff + (n + 2) * 1024 + arow + c0];
      b1f[n][1] = *(const bf16x8*)&lds[boff + (n + 2) * 1024 + arow + c1];
    }
    if (t + 2 < NT) STAGE_B(t + 2, 0);
    PHASE_BAR(); LGKM0();
    __builtin_amdgcn_s_setprio(1);
#pragma unroll
    for (int m = 0; m < 4; ++m)
#pragma unroll
      for (int n = 0; n < 2; ++n) {
        acc[m][n + 2] = MFMA16(af[m][0], b1f[n][0], acc[m][n + 2], 0, 0, 0);
        acc[m][n + 2] = MFMA16(af[m][1], b1f[n][1], acc[m][n + 2], 0, 0, 0);
      }
    __builtin_amdgcn_s_setprio(0);
    PHASE_BAR();

    // ---- P3: read A[mh1]; stage (t+2).B1; mfma quadrant (1,1) ----
#pragma unroll
    for (int m = 0; m < 4; ++m) {
      af[m][0] = *(const bf16x8*)&lds[aoff + 4096 + m * 1024 + arow + c0];
      af[m][1] = *(const bf16x8*)&lds[aoff + 4096 + m * 1024 + arow + c1];
    }
    if (t + 2 < NT) STAGE_B(t + 2, 1);
    PHASE_BAR(); LGKM0();
    __builtin_amdgcn_s_setprio(1);
#pragma unroll
    for (int m = 0; m < 4; ++m)
#pragma unroll
      for (int n = 0; n < 2; ++n) {
        acc[m + 4][n + 2] = MFMA16(af[m][0], b1f[n][0], acc[m + 4][n + 2], 0, 0, 0);
        acc[m + 4][n + 2] = MFMA16(af[m][1], b1f[n][1], acc[m + 4][n + 2], 0, 0, 0);
      }
    __builtin_amdgcn_s_setprio(0);
    PHASE_BAR();

    // ---- P4: no reads (reuse af, b0f); stage (t+2).A0; boundary vmcnt ----
    if (t + 2 < NT) {
      STAGE_A(t + 2, 0);
      __builtin_amdgcn_sched_barrier(0);
      asm volatile("s_waitcnt vmcnt(6)");
    } else {
      asm volatile("s_waitcnt vmcnt(0)");
    }
    PHASE_BAR(); LGKM0();
    __builtin_amdgcn_s_setprio(1);
#pragma unroll
    for (int m = 0; m < 4; ++m)
#pragma unroll
      for (int n = 0; n < 2; ++n) {
        acc[m + 4][n] = MFMA16(af[m][0], b0f[n][0], acc[m + 4][n], 0, 0, 0);
        acc[m + 4][n] = MFMA16(af[m][1], b0f[n][1], acc[m + 4][n], 0, 0, 0);
      }
    __builtin_amdgcn_s_setprio(0);
    PHASE_BAR();
  }

  // ---- epilogue: C/D layout col=lane&15, row=(lane>>4)*4+reg ----
  const int colBase = bn * 256 + wn * 64 + (l & 15);
  float bv[4];
#pragma unroll
  for (int n = 0; n < 4; ++n) bv[n] = bias[colBase + n * 16];
#pragma unroll
  for (int mi = 0; mi < 8; ++mi) {
    const int row = bm * 256 + wm * 128 + mi * 16 + (l >> 4) * 4;
#pragma unroll
    for (int j = 0; j < 4; ++j) {
      float* orow = out + (size_t)(row + j) * N_OUT + colBase;
#pragma unroll
      for (int n = 0; n < 4; ++n) orow[n * 16] = acc[mi][n][j] + bv[n];
    }
  }
}

extern "C" void kernel_launch(void* const* d_in, const int* in_sizes, int n_in,
                              void* d_out, int out_size, void* d_ws, size_t ws_size,
                              hipStream_t stream) {
  const float* x  = (const float*)d_in[0];
  const float* Wb = (const float*)d_in[1];
  const float* bb = (const float*)d_in[2];
  const float* Am = (const float*)d_in[3];
  const float* Bm = (const float*)d_in[4];
  const float* Wr = (const float*)d_in[5];
  const int* topk = (const int*)d_in[6];
  float* out = (float*)d_out;

  u16* Xa = (u16*)d_ws;                          // 8192*5120 bf16
  u16* Wa = Xa + (size_t)M_TOT * K_TOT;          // 4096*5120 bf16

  (void)hipFuncSetAttribute((const void*)gemm_aug,
                            hipFuncAttributeMaxDynamicSharedMemorySize, 131072);

  hipLaunchKernelGGL(build_waug,  dim3(N_OUT),      dim3(256), 0, stream, Wb, Bm, Wa);
  hipLaunchKernelGGL(prep_tokens, dim3(M_TOT / TM), dim3(256), 0, stream, x, Wr, Am, topk, Xa);
  hipLaunchKernelGGL(gemm_aug,    dim3(512),        dim3(512), 131072, stream, Xa, Wa, bb, out);
}

// Round 4
// 464.420 us; speedup vs baseline: 4.5732x; 1.2045x over previous
//
#include <hip/hip_runtime.h>
#include <hip/hip_bf16.h>
#include <cstdint>
#include <cmath>

// ResMoELoRALinear fused as ONE bf16 GEMM with augmented K:
//   out[8192,4096] = [x_bf16 | P] (8192x5120) @ [W_base | Bflat]^T (4096x5120) + b_base
// r4: prep rewritten as MFMA mini-GEMM. Router logits via bf16-triple
// (xh*wh + xh*wl + xl*wh ~= f32 fidelity for expert selection); h in bf16.
// gemm_aug = 256^2 8-phase template (T1+T2+T3/T4+T5), unchanged from r3.

#define M_TOT 8192
#define N_OUT 4096
#define K_IN  4096
#define K_TOT 5120
#define NEXP  16
#define NRES  64
#define NT    (K_TOT / 64)   // 80 K-tiles

typedef __bf16 bf16x8 __attribute__((ext_vector_type(8)));
typedef float  f32x4  __attribute__((ext_vector_type(4)));
using u16 = unsigned short;

__device__ __forceinline__ u16 f2bf(float f) {
  union { float f; unsigned u; } v; v.f = f;
  unsigned u = v.u;
  return (u16)((u + 0x7FFFu + ((u >> 16) & 1u)) >> 16);   // RNE
}
__device__ __forceinline__ float bf2f(u16 h) {
  union { unsigned u; float f; } v; v.u = ((unsigned)h) << 16;
  return v.f;
}

__device__ __forceinline__ void gload_lds16(const void* g, void* l) {
  const __attribute__((address_space(1))) unsigned* gp =
      (const __attribute__((address_space(1))) unsigned*)(unsigned long long)(uintptr_t)g;
  __attribute__((address_space(3))) unsigned* lp =
      (__attribute__((address_space(3))) unsigned*)(unsigned)(uintptr_t)l;
  __builtin_amdgcn_global_load_lds(gp, lp, 16, 0, 0);
}

#define MFMA16 __builtin_amdgcn_mfma_f32_16x16x32_bf16

// ---------------- Kernel 1: W_aug = [W_base | Bflat] as bf16 ----------------
__global__ __launch_bounds__(256) void build_waug(const float* __restrict__ Wb,
                                                  const float* __restrict__ Bm,
                                                  u16* __restrict__ Wa) {
  const int d = blockIdx.x;
  const int tid = threadIdx.x;
#pragma unroll
  for (int it = 0; it < 5; ++it) {
    int j = tid + it * 256;
    int kcol = j * 4;
    float4 v;
    if (kcol < K_IN) {
      v = *(const float4*)(Wb + (size_t)d * K_IN + kcol);
    } else {
      int kk = kcol - K_IN;
      int n = kk >> 6, r = kk & 63;
      v = *(const float4*)(Bm + ((size_t)n * N_OUT + d) * NRES + r);
    }
    ushort4 o;
    o.x = f2bf(v.x); o.y = f2bf(v.y); o.z = f2bf(v.z); o.w = f2bf(v.w);
    *(ushort4*)(Wa + (size_t)d * K_TOT + kcol) = o;
  }
}

// ---- Kernel 2 (v3): MFMA prep. 32 tokens/block, K-chunks of 64. ----
// H[32][80]: cols 0-15 = router logits (3-term bf16 ~ f32), 16-79 = h (bf16).
// M rows in LDS: 0-15 WrHi, 16-79 A, 80-95 WrLo.
// LDS per buf: xh[32][72], xl[32][72], Ms[96][72] u16 (stride 72: 16B-aligned,
// 144B row = 4-bank diagonal shift). Double-buffered. arr/wexp overlay buf0.

#define PSTR 72
#define BUFB 23040            // bytes per buffer: (32+32+96)*72*2

__global__ __launch_bounds__(256) void prep_tokens(const float* __restrict__ x,
                                                   const float* __restrict__ Wr,
                                                   const float* __restrict__ Amat,
                                                   const int* __restrict__ topk_p,
                                                   u16* __restrict__ Xa) {
  __shared__ __align__(16) char smem[2 * BUFB];
  const int tid = threadIdx.x;
  const int w = tid >> 6, l = tid & 63;
  const int l15 = l & 15, l4 = l >> 4;
  const int rt = w >> 1, cg = w & 1;
  const int token0 = blockIdx.x * 32;

  f32x4 acc[3] = {};   // cg==0: ct0(router), ct1 ; cg==1: ct2, ct3, ct4

  // ---- staging helper (macro to keep everything statically indexed) ----
#define STAGE_CHUNK(kc, buf) do {                                              \
    u16* xh_ = (u16*)(smem + (buf) * BUFB);                                    \
    u16* xl_ = xh_ + 32 * PSTR;                                                \
    u16* Ms_ = xl_ + 32 * PSTR;                                                \
    const int k0_ = (kc) * 64;                                                 \
    _Pragma("unroll")                                                          \
    for (int it = 0; it < 2; ++it) {                                           \
      int i_ = tid + it * 256;                                                 \
      int row_ = i_ >> 4, c4_ = (i_ & 15) * 4;                                 \
      float4 v_ = *(const float4*)(x + (size_t)(token0 + row_) * K_IN + k0_ + c4_); \
      ushort4 h_;                                                              \
      h_.x = f2bf(v_.x); h_.y = f2bf(v_.y); h_.z = f2bf(v_.z); h_.w = f2bf(v_.w); \
      ushort4 lo_;                                                             \
      lo_.x = f2bf(v_.x - bf2f(h_.x)); lo_.y = f2bf(v_.y - bf2f(h_.y));        \
      lo_.z = f2bf(v_.z - bf2f(h_.z)); lo_.w = f2bf(v_.w - bf2f(h_.w));        \
      *(ushort4*)&xh_[row_ * PSTR + c4_] = h_;                                 \
      *(ushort4*)&xl_[row_ * PSTR + c4_] = lo_;                                \
      *(ushort4*)(Xa + (size_t)(token0 + row_) * K_TOT + k0_ + c4_) = h_;      \
    }                                                                          \
    _Pragma("unroll")                                                          \
    for (int it = 0; it < 6; ++it) {                                           \
      int j_ = tid + it * 256;                                                 \
      int row_ = j_ >> 4, c4_ = (j_ & 15) * 4;                                 \
      const float* src_ = (row_ < 16) ? (Wr + (size_t)row_ * K_IN)             \
                        : (row_ < 80) ? (Amat + (size_t)(row_ - 16) * K_IN)    \
                                      : (Wr + (size_t)(row_ - 80) * K_IN);     \
      float4 v_ = *(const float4*)(src_ + k0_ + c4_);                          \
      ushort4 o_;                                                              \
      o_.x = f2bf(v_.x); o_.y = f2bf(v_.y); o_.z = f2bf(v_.z); o_.w = f2bf(v_.w); \
      if (row_ >= 80) {                                                        \
        o_.x = f2bf(v_.x - bf2f(o_.x)); o_.y = f2bf(v_.y - bf2f(o_.y));        \
        o_.z = f2bf(v_.z - bf2f(o_.z)); o_.w = f2bf(v_.w - bf2f(o_.w));        \
      }                                                                        \
      *(ushort4*)&Ms_[row_ * PSTR + c4_] = o_;                                 \
    }                                                                          \
  } while (0)

  STAGE_CHUNK(0, 0);
  __syncthreads();

  for (int kc = 0; kc < K_IN / 64; ++kc) {
    const int cur = kc & 1;
    if (kc + 1 < K_IN / 64) {
      if ((kc + 1) & 1) STAGE_CHUNK(kc + 1, 1);
      else              STAGE_CHUNK(kc + 1, 0);
    }
    // compute on buf cur
    {
      const u16* xh_ = (const u16*)(smem + cur * BUFB);
      const u16* xl_ = xh_ + 32 * PSTR;
      const u16* Ms_ = xl_ + 32 * PSTR;
      const int arow = (rt * 16 + l15) * PSTR;
#pragma unroll
      for (int ks = 0; ks < 2; ++ks) {
        const int fo = ks * 32 + l4 * 8;
        const bf16x8 ah = *(const bf16x8*)&xh_[arow + fo];
        if (cg == 0) {
          const bf16x8 al = *(const bf16x8*)&xl_[arow + fo];
          const bf16x8 b0 = *(const bf16x8*)&Ms_[(0 * 16 + l15) * PSTR + fo];
          const bf16x8 b1 = *(const bf16x8*)&Ms_[(1 * 16 + l15) * PSTR + fo];
          const bf16x8 b5 = *(const bf16x8*)&Ms_[(5 * 16 + l15) * PSTR + fo];
          acc[0] = MFMA16(ah, b0, acc[0], 0, 0, 0);
          acc[0] = MFMA16(al, b0, acc[0], 0, 0, 0);
          acc[0] = MFMA16(ah, b5, acc[0], 0, 0, 0);
          acc[1] = MFMA16(ah, b1, acc[1], 0, 0, 0);
        } else {
          const bf16x8 b2 = *(const bf16x8*)&Ms_[(2 * 16 + l15) * PSTR + fo];
          const bf16x8 b3 = *(const bf16x8*)&Ms_[(3 * 16 + l15) * PSTR + fo];
          const bf16x8 b4 = *(const bf16x8*)&Ms_[(4 * 16 + l15) * PSTR + fo];
          acc[0] = MFMA16(ah, b2, acc[0], 0, 0, 0);
          acc[1] = MFMA16(ah, b3, acc[1], 0, 0, 0);
          acc[2] = MFMA16(ah, b4, acc[2], 0, 0, 0);
        }
      }
    }
    __syncthreads();
  }

  // ---- epilogue: H -> LDS (overlay buf0), softmax/top-k, P write ----
  float* arr  = (float*)smem;              // [32][80]
  float* wexp = (float*)(smem + 10240);    // [32][16]
  {
    const int row0 = rt * 16 + l4 * 4;
    if (cg == 0) {
#pragma unroll
      for (int ct = 0; ct < 2; ++ct)
#pragma unroll
        for (int j = 0; j < 4; ++j)
          arr[(row0 + j) * 80 + ct * 16 + l15] = acc[ct][j];
    } else {
#pragma unroll
      for (int ct = 0; ct < 3; ++ct)
#pragma unroll
        for (int j = 0; j < 4; ++j)
          arr[(row0 + j) * 80 + 32 + ct * 16 + l15] = acc[ct][j];
    }
  }
  __syncthreads();

  if (tid < 32) {
    const int tt = tid;
    const int k = *topk_p;
    float p[16];
    float mx = arr[tt * 80 + 0];
#pragma unroll
    for (int e = 1; e < 16; ++e) mx = fmaxf(mx, arr[tt * 80 + e]);
    float Z = 0.f;
#pragma unroll
    for (int e = 0; e < 16; ++e) { p[e] = expf(arr[tt * 80 + e] - mx); Z += p[e]; }
    const float invZ = 1.f / Z;
#pragma unroll
    for (int e = 0; e < 16; ++e) p[e] *= invZ;
    float wv[16];
    if (k <= 0 || k >= NEXP) {
#pragma unroll
      for (int e = 0; e < 16; ++e) wv[e] = p[e];
    } else {
      unsigned um = 0; float ssum = 0.f;
      for (int kk = 0; kk < k; ++kk) {
        int best = 0; float bv = -1.f;
#pragma unroll
        for (int e = 0; e < 16; ++e)
          if (!((um >> e) & 1u) && p[e] > bv) { bv = p[e]; best = e; }
        um |= 1u << best; ssum += bv;
      }
      const float inv = 1.f / (ssum + 1e-6f);
#pragma unroll
      for (int e = 0; e < 16; ++e) wv[e] = ((um >> e) & 1u) ? p[e] * inv : 0.f;
    }
#pragma unroll
    for (int e = 0; e < 16; ++e) wexp[tt * 16 + e] = wv[e];
  }
  __syncthreads();

#pragma unroll
  for (int it = 0; it < 16; ++it) {
    int idx = tid + it * 256;             // 0..4095 over 32 tokens x 128 groups
    int tt = idx >> 7, c8 = idx & 127;
    int n = c8 >> 3, r0 = (c8 & 7) * 8;
    const float wv = wexp[tt * 16 + n];
    const float* hb = &arr[tt * 80 + 16 + r0];
    ushort4 lo, hi;
    lo.x = f2bf(wv * hb[0]); lo.y = f2bf(wv * hb[1]);
    lo.z = f2bf(wv * hb[2]); lo.w = f2bf(wv * hb[3]);
    hi.x = f2bf(wv * hb[4]); hi.y = f2bf(wv * hb[5]);
    hi.z = f2bf(wv * hb[6]); hi.w = f2bf(wv * hb[7]);
    u16* dst = Xa + (size_t)(token0 + tt) * K_TOT + K_IN + c8 * 8;
    *(ushort4*)(dst) = lo;
    *(ushort4*)(dst + 4) = hi;
  }
}

// ------ Kernel 3: 256^2 8-phase bf16 GEMM: C = Xa * Wa^T + bias ------
#define PHASE_BAR() do {                      \
  __builtin_amdgcn_sched_barrier(0);          \
  __builtin_amdgcn_s_barrier();               \
  __builtin_amdgcn_sched_barrier(0);          \
} while (0)

#define LGKM0() do {                          \
  asm volatile("s_waitcnt lgkmcnt(0)");       \
  __builtin_amdgcn_sched_barrier(0);          \
} while (0)

__global__ __launch_bounds__(512, 2) void gemm_aug(const u16* __restrict__ Xa,
                                                   const u16* __restrict__ Wa,
                                                   const float* __restrict__ bias,
                                                   float* __restrict__ out) {
  extern __shared__ u16 lds[];
  const int tid = threadIdx.x;
  const int w = tid >> 6, l = tid & 63;
  const int bid = blockIdx.x;
  const int wg = (bid & 7) * 64 + (bid >> 3);
  const int bm = wg >> 4, bn = wg & 15;
  const int wm = w >> 2, wn = w & 3;

  const int srow = w * 8 + (l >> 3);
  const int gsw = ((l & 7) ^ (l >> 3)) * 8;
  const u16* sA = Xa + (size_t)(bm * 256 + srow) * K_TOT + gsw;
  const u16* sB = Wa + (size_t)(bn * 256 + srow) * K_TOT + gsw;
  const int stq = w * 512;

  const int arow = (l & 15) * 64;
  const int c0 = (((l >> 4) + 0) ^ (l & 7)) * 8;
  const int c1 = (((l >> 4) + 4) ^ (l & 7)) * 8;

  f32x4 acc[8][4] = {};

#define STAGE_A(tile, half) do {                                               \
    const u16* s_ = sA + (size_t)(half) * 128 * K_TOT + (size_t)(tile) * 64;   \
    const int d_ = ((tile) & 1) * 32768 + (half) * 8192 + stq;                 \
    gload_lds16(s_, &lds[d_]);                                                 \
    gload_lds16(s_ + (size_t)64 * K_TOT, &lds[d_ + 4096]);                     \
  } while (0)
#define STAGE_B(tile, half) do {                                               \
    const u16* s_ = sB + (size_t)(half) * 128 * K_TOT + (size_t)(tile) * 64;   \
    const int d_ = ((tile) & 1) * 32768 + 16384 + (half) * 8192 + stq;         \
    gload_lds16(s_, &lds[d_]);                                                 \
    gload_lds16(s_ + (size_t)64 * K_TOT, &lds[d_ + 4096]);                     \
  } while (0)

  STAGE_B(0, 0); STAGE_B(0, 1); STAGE_A(0, 0); STAGE_A(0, 1);
  STAGE_B(1, 0); STAGE_B(1, 1); STAGE_A(1, 0);
  __builtin_amdgcn_sched_barrier(0);
  asm volatile("s_waitcnt vmcnt(6)");
  PHASE_BAR();

  for (int t = 0; t < NT; ++t) {
    const int bufOff = (t & 1) * 32768;
    const int aoff = bufOff + wm * 8192;
    const int boff = bufOff + 16384 + (wn >> 1) * 8192 + (wn & 1) * 4096;
    bf16x8 af[4][2], b0f[2][2], b1f[2][2];

    // ---- P1 ----
#pragma unroll
    for (int m = 0; m < 4; ++m) {
      af[m][0] = *(const bf16x8*)&lds[aoff + m * 1024 + arow + c0];
      af[m][1] = *(const bf16x8*)&lds[aoff + m * 1024 + arow + c1];
    }
#pragma unroll
    for (int n = 0; n < 2; ++n) {
      b0f[n][0] = *(const bf16x8*)&lds[boff + n * 1024 + arow + c0];
      b0f[n][1] = *(const bf16x8*)&lds[boff + n * 1024 + arow + c1];
    }
    if (t + 1 < NT) STAGE_A(t + 1, 1);
    PHASE_BAR(); LGKM0();
    __builtin_amdgcn_s_setprio(1);
#pragma unroll
    for (int m = 0; m < 4; ++m)
#pragma unroll
      for (int n = 0; n < 2; ++n) {
        acc[m][n] = MFMA16(af[m][0], b0f[n][0], acc[m][n], 0, 0, 0);
        acc[m][n] = MFMA16(af[m][1], b0f[n][1], acc[m][n], 0, 0, 0);
      }
    __builtin_amdgcn_s_setprio(0);
    PHASE_BAR();

    // ---- P2 ----
#pragma unroll
    for (int n = 0; n < 2; ++n) {
      b1f[n][0] = *(const bf16x8*)&lds[boff + (n + 2) * 1024 + arow + c0];
      b1f[n][1] = *(const bf16x8*)&lds[boff + (n + 2) * 1024 + arow + c1];
    }
    if (t + 2 < NT) STAGE_B(t + 2, 0);
    PHASE_BAR(); LGKM0();
    __builtin_amdgcn_s_setprio(1);
#pragma unroll
    for (int m = 0; m < 4; ++m)
#pragma unroll
      for (int n = 0; n < 2; ++n) {
        acc[m][n + 2] = MFMA16(af[m][0], b1f[n][0], acc[m][n + 2], 0, 0, 0);
        acc[m][n + 2] = MFMA16(af[m][1], b1f[n][1], acc[m][n + 2], 0, 0, 0);
      }
    __builtin_amdgcn_s_setprio(0);
    PHASE_BAR();

    // ---- P3 ----
#pragma unroll
    for (int m = 0; m < 4; ++m) {
      af[m][0] = *(const bf16x8*)&lds[aoff + 4096 + m * 1024 + arow + c0];
      af[m][1] = *(const bf16x8*)&lds[aoff + 4096 + m * 1024 + arow + c1];
    }
    if (t + 2 < NT) STAGE_B(t + 2, 1);
    PHASE_BAR(); LGKM0();
    __builtin_amdgcn_s_setprio(1);
#pragma unroll
    for (int m = 0; m < 4; ++m)
#pragma unroll
      for (int n = 0; n < 2; ++n) {
        acc[m + 4][n + 2] = MFMA16(af[m][0], b1f[n][0], acc[m + 4][n + 2], 0, 0, 0);
        acc[m + 4][n + 2] = MFMA16(af[m][1], b1f[n][1], acc[m + 4][n + 2], 0, 0, 0);
      }
    __builtin_amdgcn_s_setprio(0);
    PHASE_BAR();

    // ---- P4 ----
    if (t + 2 < NT) {
      STAGE_A(t + 2, 0);
      __builtin_amdgcn_sched_barrier(0);
      asm volatile("s_waitcnt vmcnt(6)");
    } else {
      asm volatile("s_waitcnt vmcnt(0)");
    }
    PHASE_BAR(); LGKM0();
    __builtin_amdgcn_s_setprio(1);
#pragma unroll
    for (int m = 0; m < 4; ++m)
#pragma unroll
      for (int n = 0; n < 2; ++n) {
        acc[m + 4][n] = MFMA16(af[m][0], b0f[n][0], acc[m + 4][n], 0, 0, 0);
        acc[m + 4][n] = MFMA16(af[m][1], b0f[n][1], acc[m + 4][n], 0, 0, 0);
      }
    __builtin_amdgcn_s_setprio(0);
    PHASE_BAR();
  }

  const int colBase = bn * 256 + wn * 64 + (l & 15);
  float bv[4];
#pragma unroll
  for (int n = 0; n < 4; ++n) bv[n] = bias[colBase + n * 16];
#pragma unroll
  for (int mi = 0; mi < 8; ++mi) {
    const int row = bm * 256 + wm * 128 + mi * 16 + (l >> 4) * 4;
#pragma unroll
    for (int j = 0; j < 4; ++j) {
      float* orow = out + (size_t)(row + j) * N_OUT + colBase;
#pragma unroll
      for (int n = 0; n < 4; ++n) orow[n * 16] = acc[mi][n][j] + bv[n];
    }
  }
}

extern "C" void kernel_launch(void* const* d_in, const int* in_sizes, int n_in,
                              void* d_out, int out_size, void* d_ws, size_t ws_size,
                              hipStream_t stream) {
  const float* x  = (const float*)d_in[0];
  const float* Wb = (const float*)d_in[1];
  const float* bb = (const float*)d_in[2];
  const float* Am = (const float*)d_in[3];
  const float* Bm = (const float*)d_in[4];
  const float* Wr = (const float*)d_in[5];
  const int* topk = (const int*)d_in[6];
  float* out = (float*)d_out;

  u16* Xa = (u16*)d_ws;                          // 8192*5120 bf16
  u16* Wa = Xa + (size_t)M_TOT * K_TOT;          // 4096*5120 bf16

  (void)hipFuncSetAttribute((const void*)gemm_aug,
                            hipFuncAttributeMaxDynamicSharedMemorySize, 131072);

  hipLaunchKernelGGL(build_waug,  dim3(N_OUT),      dim3(256), 0, stream, Wb, Bm, Wa);
  hipLaunchKernelGGL(prep_tokens, dim3(M_TOT / 32), dim3(256), 0, stream, x, Wr, Am, topk, Xa);
  hipLaunchKernelGGL(gemm_aug,    dim3(512),        dim3(512), 131072, stream, Xa, Wa, bb, out);
}

// Round 5
// 392.364 us; speedup vs baseline: 5.4131x; 1.1836x over previous
//
#include <hip/hip_runtime.h>
#include <hip/hip_bf16.h>
#include <cstdint>
#include <cmath>

// ResMoELoRALinear fused as ONE bf16 GEMM with augmented K:
//   out[8192,4096] = [x_bf16 | P] (8192x5120) @ [W_base | Bflat]^T (4096x5120) + b_base
// r5: prep staging de-VALU'd — M = [WrHi;A;WrLo] precomputed once (bf16,
// chunk-blocked, granule-XOR-swizzled) in build_waug, prep stages it via
// global_load_lds DMA. Native (__bf16) casts (compiler emits cvt_pk).
// gemm_aug byte-identical to r3/r4 (control for the 217-vs-309 µs mystery).

#define M_TOT 8192
#define N_OUT 4096
#define K_IN  4096
#define K_TOT 5120
#define NEXP  16
#define NRES  64
#define NT    (K_TOT / 64)   // 80 K-tiles
#define NCH   (K_IN / 64)    // 64 prep chunks

typedef __bf16 bf16x8 __attribute__((ext_vector_type(8)));
typedef float  f32x4  __attribute__((ext_vector_type(4)));
using u16 = unsigned short;

__device__ __forceinline__ u16 bfbits(float f) {
  __bf16 h = (__bf16)f;                  // RNE via v_cvt (compiler may pack)
  union { __bf16 h; u16 u; } c; c.h = h;
  return c.u;
}
__device__ __forceinline__ float lopart(float f) {
  __bf16 h = (__bf16)f;
  return f - (float)h;
}

__device__ __forceinline__ void gload_lds16(const void* g, void* l) {
  const __attribute__((address_space(1))) unsigned* gp =
      (const __attribute__((address_space(1))) unsigned*)(unsigned long long)(uintptr_t)g;
  __attribute__((address_space(3))) unsigned* lp =
      (__attribute__((address_space(3))) unsigned*)(unsigned)(uintptr_t)l;
  __builtin_amdgcn_global_load_lds(gp, lp, 16, 0, 0);
}

#define MFMA16 __builtin_amdgcn_mfma_f32_16x16x32_bf16

// ------- Kernel 1: W_aug = [W_base | Bflat] bf16  +  Ms_pre emit -------
// blocks 0..4095: Wa rows. blocks 4096..4191: Ms_pre rows.
// Ms_pre layout: [chunk 64][row 96][g 8][e 8] u16, stored granule g' = g^(row&7).
// rows 0-15 = WrHi, 16-79 = A, 80-95 = WrLo.
__global__ __launch_bounds__(256) void build_waug(const float* __restrict__ Wb,
                                                  const float* __restrict__ Bm,
                                                  const float* __restrict__ Wr,
                                                  const float* __restrict__ Amat,
                                                  u16* __restrict__ Wa,
                                                  u16* __restrict__ Msp) {
  const int bidx = blockIdx.x;
  const int tid = threadIdx.x;
  if (bidx < N_OUT) {
    const int d = bidx;
#pragma unroll
    for (int it = 0; it < 5; ++it) {
      int j = tid + it * 256;
      int kcol = j * 4;
      float4 v;
      if (kcol < K_IN) {
        v = *(const float4*)(Wb + (size_t)d * K_IN + kcol);
      } else {
        int kk = kcol - K_IN;
        int n = kk >> 6, r = kk & 63;
        v = *(const float4*)(Bm + ((size_t)n * N_OUT + d) * NRES + r);
      }
      ushort4 o;
      o.x = bfbits(v.x); o.y = bfbits(v.y); o.z = bfbits(v.z); o.w = bfbits(v.w);
      *(ushort4*)(Wa + (size_t)d * K_TOT + kcol) = o;
    }
  } else {
    const int row = bidx - N_OUT;           // 0..95
    const float* src = (row < 16) ? (Wr + (size_t)row * K_IN)
                     : (row < 80) ? (Amat + (size_t)(row - 16) * K_IN)
                                  : (Wr + (size_t)(row - 80) * K_IN);
    const bool lo = (row >= 80);
#pragma unroll
    for (int it = 0; it < 2; ++it) {
      int gi = tid + it * 256;              // granule 0..511
      int col = gi * 8;
      float4 a = *(const float4*)(src + col);
      float4 b = *(const float4*)(src + col + 4);
      float v0 = a.x, v1 = a.y, v2 = a.z, v3 = a.w;
      float v4 = b.x, v5 = b.y, v6 = b.z, v7 = b.w;
      if (lo) { v0 = lopart(v0); v1 = lopart(v1); v2 = lopart(v2); v3 = lopart(v3);
                v4 = lopart(v4); v5 = lopart(v5); v6 = lopart(v6); v7 = lopart(v7); }
      ushort4 o0, o1;
      o0.x = bfbits(v0); o0.y = bfbits(v1); o0.z = bfbits(v2); o0.w = bfbits(v3);
      o1.x = bfbits(v4); o1.y = bfbits(v5); o1.z = bfbits(v6); o1.w = bfbits(v7);
      u16* dst = Msp + ((size_t)(((gi >> 3) * 96 + row) * 8 + ((gi & 7) ^ (row & 7)))) * 8;
      *(ushort4*)(dst) = o0;
      *(ushort4*)(dst + 4) = o1;
    }
  }
}

// ---- Kernel 2 (v4): MFMA prep, DMA-staged M. 32 tokens/block, K-chunks of 64. ----
// LDS per buf (u16): xh[32][72], xl[32][72], Ms[96*64 linear, swizzled granules].
// BUF_U16 = 2304+2304+6144 = 10752 (21.5 KB); x2 buf = 43 KB -> 3 blocks/CU.
#define PSTR 72
#define BUF_U16 10752

__global__ __launch_bounds__(256) void prep_tokens(const float* __restrict__ x,
                                                   const u16* __restrict__ Msp,
                                                   const int* __restrict__ topk_p,
                                                   u16* __restrict__ Xa) {
  __shared__ __align__(16) u16 smem[2 * BUF_U16];
  const int tid = threadIdx.x;
  const int w = tid >> 6, l = tid & 63;
  const int l15 = l & 15, l4 = l >> 4;
  const int rt = w >> 1, cg = w & 1;
  const int token0 = blockIdx.x * 32;

  f32x4 acc[3] = {};

#define STAGE_CHUNK(kc, buf) do {                                              \
    u16* xh_ = smem + (buf) * BUF_U16;                                         \
    u16* xl_ = xh_ + 32 * PSTR;                                                \
    u16* Ms_ = xl_ + 32 * PSTR;                                                \
    const int k0_ = (kc) * 64;                                                 \
    _Pragma("unroll")                                                          \
    for (int it = 0; it < 3; ++it) {                                           \
      gload_lds16(Msp + (size_t)(kc) * 6144 + (size_t)(it * 256 + tid) * 8,    \
                  Ms_ + it * 2048 + w * 512);                                  \
    }                                                                          \
    _Pragma("unroll")                                                          \
    for (int it = 0; it < 2; ++it) {                                           \
      int i_ = tid + it * 256;                                                 \
      int row_ = i_ >> 4, c4_ = (i_ & 15) * 4;                                 \
      float4 v_ = *(const float4*)(x + (size_t)(token0 + row_) * K_IN + k0_ + c4_); \
      ushort4 h_;                                                              \
      h_.x = bfbits(v_.x); h_.y = bfbits(v_.y);                                \
      h_.z = bfbits(v_.z); h_.w = bfbits(v_.w);                                \
      ushort4 lo_;                                                             \
      lo_.x = bfbits(lopart(v_.x)); lo_.y = bfbits(lopart(v_.y));              \
      lo_.z = bfbits(lopart(v_.z)); lo_.w = bfbits(lopart(v_.w));              \
      *(ushort4*)&xh_[row_ * PSTR + c4_] = h_;                                 \
      *(ushort4*)&xl_[row_ * PSTR + c4_] = lo_;                                \
      *(ushort4*)(Xa + (size_t)(token0 + row_) * K_TOT + k0_ + c4_) = h_;      \
    }                                                                          \
  } while (0)

  // Ms LDS read: row = tb*16+l15, granule q = ks*4+l4, slot q^(l15&7)
#define MS_FRAG(Ms_, tb, ks) \
  (*(const bf16x8*)&(Ms_)[(size_t)((((tb) * 16 + l15) * 8 + (((ks) * 4 + l4) ^ (l15 & 7)))) * 8])

  STAGE_CHUNK(0, 0);
  __syncthreads();

  for (int kc = 0; kc < NCH; ++kc) {
    const int cur = kc & 1;
    if (kc + 1 < NCH) {
      if ((kc + 1) & 1) STAGE_CHUNK(kc + 1, 1);
      else              STAGE_CHUNK(kc + 1, 0);
    }
    {
      const u16* xh_ = smem + cur * BUF_U16;
      const u16* xl_ = xh_ + 32 * PSTR;
      const u16* Ms_ = xl_ + 32 * PSTR;
      const int arow = (rt * 16 + l15) * PSTR;
#pragma unroll
      for (int ks = 0; ks < 2; ++ks) {
        const int fo = ks * 32 + l4 * 8;
        const bf16x8 ah = *(const bf16x8*)&xh_[arow + fo];
        if (cg == 0) {
          const bf16x8 al = *(const bf16x8*)&xl_[arow + fo];
          const bf16x8 b0 = MS_FRAG(Ms_, 0, ks);
          const bf16x8 b1 = MS_FRAG(Ms_, 1, ks);
          const bf16x8 b5 = MS_FRAG(Ms_, 5, ks);
          acc[0] = MFMA16(ah, b0, acc[0], 0, 0, 0);
          acc[0] = MFMA16(al, b0, acc[0], 0, 0, 0);
          acc[0] = MFMA16(ah, b5, acc[0], 0, 0, 0);
          acc[1] = MFMA16(ah, b1, acc[1], 0, 0, 0);
        } else {
          const bf16x8 b2 = MS_FRAG(Ms_, 2, ks);
          const bf16x8 b3 = MS_FRAG(Ms_, 3, ks);
          const bf16x8 b4 = MS_FRAG(Ms_, 4, ks);
          acc[0] = MFMA16(ah, b2, acc[0], 0, 0, 0);
          acc[1] = MFMA16(ah, b3, acc[1], 0, 0, 0);
          acc[2] = MFMA16(ah, b4, acc[2], 0, 0, 0);
        }
      }
    }
    __syncthreads();
  }

  // ---- epilogue: H -> LDS (overlay buf0), softmax/top-k, P write ----
  float* arr  = (float*)smem;                       // [32][80]
  float* wexp = (float*)((char*)smem + 10240);      // [32][16]
  {
    const int row0 = rt * 16 + l4 * 4;
    if (cg == 0) {
#pragma unroll
      for (int ct = 0; ct < 2; ++ct)
#pragma unroll
        for (int j = 0; j < 4; ++j)
          arr[(row0 + j) * 80 + ct * 16 + l15] = acc[ct][j];
    } else {
#pragma unroll
      for (int ct = 0; ct < 3; ++ct)
#pragma unroll
        for (int j = 0; j < 4; ++j)
          arr[(row0 + j) * 80 + 32 + ct * 16 + l15] = acc[ct][j];
    }
  }
  __syncthreads();

  if (tid < 32) {
    const int tt = tid;
    const int k = *topk_p;
    float p[16];
    float mx = arr[tt * 80 + 0];
#pragma unroll
    for (int e = 1; e < 16; ++e) mx = fmaxf(mx, arr[tt * 80 + e]);
    float Z = 0.f;
#pragma unroll
    for (int e = 0; e < 16; ++e) { p[e] = expf(arr[tt * 80 + e] - mx); Z += p[e]; }
    const float invZ = 1.f / Z;
#pragma unroll
    for (int e = 0; e < 16; ++e) p[e] *= invZ;
    float wv[16];
    if (k <= 0 || k >= NEXP) {
#pragma unroll
      for (int e = 0; e < 16; ++e) wv[e] = p[e];
    } else {
      unsigned um = 0; float ssum = 0.f;
      for (int kk = 0; kk < k; ++kk) {
        int best = 0; float bv = -1.f;
#pragma unroll
        for (int e = 0; e < 16; ++e)
          if (!((um >> e) & 1u) && p[e] > bv) { bv = p[e]; best = e; }
        um |= 1u << best; ssum += bv;
      }
      const float inv = 1.f / (ssum + 1e-6f);
#pragma unroll
      for (int e = 0; e < 16; ++e) wv[e] = ((um >> e) & 1u) ? p[e] * inv : 0.f;
    }
#pragma unroll
    for (int e = 0; e < 16; ++e) wexp[tt * 16 + e] = wv[e];
  }
  __syncthreads();

#pragma unroll
  for (int it = 0; it < 16; ++it) {
    int idx = tid + it * 256;             // 0..4095 over 32 tokens x 128 groups
    int tt = idx >> 7, c8 = idx & 127;
    int n = c8 >> 3, r0 = (c8 & 7) * 8;
    const float wv = wexp[tt * 16 + n];
    const float* hb = &arr[tt * 80 + 16 + r0];
    ushort4 lo, hi;
    lo.x = bfbits(wv * hb[0]); lo.y = bfbits(wv * hb[1]);
    lo.z = bfbits(wv * hb[2]); lo.w = bfbits(wv * hb[3]);
    hi.x = bfbits(wv * hb[4]); hi.y = bfbits(wv * hb[5]);
    hi.z = bfbits(wv * hb[6]); hi.w = bfbits(wv * hb[7]);
    u16* dst = Xa + (size_t)(token0 + tt) * K_TOT + K_IN + c8 * 8;
    *(ushort4*)(dst) = lo;
    *(ushort4*)(dst + 4) = hi;
  }
}

// ------ Kernel 3: 256^2 8-phase bf16 GEMM: C = Xa * Wa^T + bias ------
// (byte-identical to r3/r4 — control)
#define PHASE_BAR() do {                      \
  __builtin_amdgcn_sched_barrier(0);          \
  __builtin_amdgcn_s_barrier();               \
  __builtin_amdgcn_sched_barrier(0);          \
} while (0)

#define LGKM0() do {                          \
  asm volatile("s_waitcnt lgkmcnt(0)");       \
  __builtin_amdgcn_sched_barrier(0);          \
} while (0)

__global__ __launch_bounds__(512, 2) void gemm_aug(const u16* __restrict__ Xa,
                                                   const u16* __restrict__ Wa,
                                                   const float* __restrict__ bias,
                                                   float* __restrict__ out) {
  extern __shared__ u16 lds[];
  const int tid = threadIdx.x;
  const int w = tid >> 6, l = tid & 63;
  const int bid = blockIdx.x;
  const int wg = (bid & 7) * 64 + (bid >> 3);
  const int bm = wg >> 4, bn = wg & 15;
  const int wm = w >> 2, wn = w & 3;

  const int srow = w * 8 + (l >> 3);
  const int gsw = ((l & 7) ^ (l >> 3)) * 8;
  const u16* sA = Xa + (size_t)(bm * 256 + srow) * K_TOT + gsw;
  const u16* sB = Wa + (size_t)(bn * 256 + srow) * K_TOT + gsw;
  const int stq = w * 512;

  const int arow = (l & 15) * 64;
  const int c0 = (((l >> 4) + 0) ^ (l & 7)) * 8;
  const int c1 = (((l >> 4) + 4) ^ (l & 7)) * 8;

  f32x4 acc[8][4] = {};

#define STAGE_A(tile, half) do {                                               \
    const u16* s_ = sA + (size_t)(half) * 128 * K_TOT + (size_t)(tile) * 64;   \
    const int d_ = ((tile) & 1) * 32768 + (half) * 8192 + stq;                 \
    gload_lds16(s_, &lds[d_]);                                                 \
    gload_lds16(s_ + (size_t)64 * K_TOT, &lds[d_ + 4096]);                     \
  } while (0)
#define STAGE_B(tile, half) do {                                               \
    const u16* s_ = sB + (size_t)(half) * 128 * K_TOT + (size_t)(tile) * 64;   \
    const int d_ = ((tile) & 1) * 32768 + 16384 + (half) * 8192 + stq;         \
    gload_lds16(s_, &lds[d_]);                                                 \
    gload_lds16(s_ + (size_t)64 * K_TOT, &lds[d_ + 4096]);                     \
  } while (0)

  STAGE_B(0, 0); STAGE_B(0, 1); STAGE_A(0, 0); STAGE_A(0, 1);
  STAGE_B(1, 0); STAGE_B(1, 1); STAGE_A(1, 0);
  __builtin_amdgcn_sched_barrier(0);
  asm volatile("s_waitcnt vmcnt(6)");
  PHASE_BAR();

  for (int t = 0; t < NT; ++t) {
    const int bufOff = (t & 1) * 32768;
    const int aoff = bufOff + wm * 8192;
    const int boff = bufOff + 16384 + (wn >> 1) * 8192 + (wn & 1) * 4096;
    bf16x8 af[4][2], b0f[2][2], b1f[2][2];

    // ---- P1 ----
#pragma unroll
    for (int m = 0; m < 4; ++m) {
      af[m][0] = *(const bf16x8*)&lds[aoff + m * 1024 + arow + c0];
      af[m][1] = *(const bf16x8*)&lds[aoff + m * 1024 + arow + c1];
    }
#pragma unroll
    for (int n = 0; n < 2; ++n) {
      b0f[n][0] = *(const bf16x8*)&lds[boff + n * 1024 + arow + c0];
      b0f[n][1] = *(const bf16x8*)&lds[boff + n * 1024 + arow + c1];
    }
    if (t + 1 < NT) STAGE_A(t + 1, 1);
    PHASE_BAR(); LGKM0();
    __builtin_amdgcn_s_setprio(1);
#pragma unroll
    for (int m = 0; m < 4; ++m)
#pragma unroll
      for (int n = 0; n < 2; ++n) {
        acc[m][n] = MFMA16(af[m][0], b0f[n][0], acc[m][n], 0, 0, 0);
        acc[m][n] = MFMA16(af[m][1], b0f[n][1], acc[m][n], 0, 0, 0);
      }
    __builtin_amdgcn_s_setprio(0);
    PHASE_BAR();

    // ---- P2 ----
#pragma unroll
    for (int n = 0; n < 2; ++n) {
      b1f[n][0] = *(const bf16x8*)&lds[boff + (n + 2) * 1024 + arow + c0];
      b1f[n][1] = *(const bf16x8*)&lds[boff + (n + 2) * 1024 + arow + c1];
    }
    if (t + 2 < NT) STAGE_B(t + 2, 0);
    PHASE_BAR(); LGKM0();
    __builtin_amdgcn_s_setprio(1);
#pragma unroll
    for (int m = 0; m < 4; ++m)
#pragma unroll
      for (int n = 0; n < 2; ++n) {
        acc[m][n + 2] = MFMA16(af[m][0], b1f[n][0], acc[m][n + 2], 0, 0, 0);
        acc[m][n + 2] = MFMA16(af[m][1], b1f[n][1], acc[m][n + 2], 0, 0, 0);
      }
    __builtin_amdgcn_s_setprio(0);
    PHASE_BAR();

    // ---- P3 ----
#pragma unroll
    for (int m = 0; m < 4; ++m) {
      af[m][0] = *(const bf16x8*)&lds[aoff + 4096 + m * 1024 + arow + c0];
      af[m][1] = *(const bf16x8*)&lds[aoff + 4096 + m * 1024 + arow + c1];
    }
    if (t + 2 < NT) STAGE_B(t + 2, 1);
    PHASE_BAR(); LGKM0();
    __builtin_amdgcn_s_setprio(1);
#pragma unroll
    for (int m = 0; m < 4; ++m)
#pragma unroll
      for (int n = 0; n < 2; ++n) {
        acc[m + 4][n + 2] = MFMA16(af[m][0], b1f[n][0], acc[m + 4][n + 2], 0, 0, 0);
        acc[m + 4][n + 2] = MFMA16(af[m][1], b1f[n][1], acc[m + 4][n + 2], 0, 0, 0);
      }
    __builtin_amdgcn_s_setprio(0);
    PHASE_BAR();

    // ---- P4 ----
    if (t + 2 < NT) {
      STAGE_A(t + 2, 0);
      __builtin_amdgcn_sched_barrier(0);
      asm volatile("s_waitcnt vmcnt(6)");
    } else {
      asm volatile("s_waitcnt vmcnt(0)");
    }
    PHASE_BAR(); LGKM0();
    __builtin_amdgcn_s_setprio(1);
#pragma unroll
    for (int m = 0; m < 4; ++m)
#pragma unroll
      for (int n = 0; n < 2; ++n) {
        acc[m + 4][n] = MFMA16(af[m][0], b0f[n][0], acc[m + 4][n], 0, 0, 0);
        acc[m + 4][n] = MFMA16(af[m][1], b0f[n][1], acc[m + 4][n], 0, 0, 0);
      }
    __builtin_amdgcn_s_setprio(0);
    PHASE_BAR();
  }

  const int colBase = bn * 256 + wn * 64 + (l & 15);
  float bv[4];
#pragma unroll
  for (int n = 0; n < 4; ++n) bv[n] = bias[colBase + n * 16];
#pragma unroll
  for (int mi = 0; mi < 8; ++mi) {
    const int row = bm * 256 + wm * 128 + mi * 16 + (l >> 4) * 4;
#pragma unroll
    for (int j = 0; j < 4; ++j) {
      float* orow = out + (size_t)(row + j) * N_OUT + colBase;
#pragma unroll
      for (int n = 0; n < 4; ++n) orow[n * 16] = acc[mi][n][j] + bv[n];
    }
  }
}

extern "C" void kernel_launch(void* const* d_in, const int* in_sizes, int n_in,
                              void* d_out, int out_size, void* d_ws, size_t ws_size,
                              hipStream_t stream) {
  const float* x  = (const float*)d_in[0];
  const float* Wb = (const float*)d_in[1];
  const float* bb = (const float*)d_in[2];
  const float* Am = (const float*)d_in[3];
  const float* Bm = (const float*)d_in[4];
  const float* Wr = (const float*)d_in[5];
  const int* topk = (const int*)d_in[6];
  float* out = (float*)d_out;

  u16* Xa  = (u16*)d_ws;                          // 8192*5120 bf16
  u16* Wa  = Xa + (size_t)M_TOT * K_TOT;          // 4096*5120 bf16
  u16* Msp = Wa + (size_t)N_OUT * K_TOT;          // 64*96*64 bf16 (786 KB)

  (void)hipFuncSetAttribute((const void*)gemm_aug,
                            hipFuncAttributeMaxDynamicSharedMemorySize, 131072);

  hipLaunchKernelGGL(build_waug,  dim3(N_OUT + 96), dim3(256), 0, stream,
                     Wb, Bm, Wr, Am, Wa, Msp);
  hipLaunchKernelGGL(prep_tokens, dim3(M_TOT / 32), dim3(256), 0, stream,
                     x, Msp, topk, Xa);
  hipLaunchKernelGGL(gemm_aug,    dim3(512),        dim3(512), 131072, stream,
                     Xa, Wa, bb, out);
}

// Round 7
// 387.493 us; speedup vs baseline: 5.4811x; 1.0126x over previous
//
#include <hip/hip_runtime.h>
#include <hip/hip_bf16.h>
#include <cstdint>
#include <cmath>

// ResMoELoRALinear fused as ONE bf16 GEMM with augmented K:
//   out[8192,4096] = [x_bf16 | P] (8192x5120) @ [W_base | Bflat]^T (4096x5120) + b_base
// r7: revert gemm to the known-correct 16x16x32 fragments (r6's 32x32 port
// failed with K-slice-scale error — suspected asymmetric A/B lane-group map
// on mfma_32x32x16; logged, not retried). K-loop restructured to the literal
// m201 template: 2 K-tiles unrolled per iteration, buffer parity compile-time,
// + lgkmcnt(8) pre-drain in the 12-ds_read phase. prep/build identical to r5.

#define M_TOT 8192
#define N_OUT 4096
#define K_IN  4096
#define K_TOT 5120
#define NEXP  16
#define NRES  64
#define NT    (K_TOT / 64)   // 80 K-tiles
#define NCH   (K_IN / 64)    // 64 prep chunks

typedef __bf16 bf16x8 __attribute__((ext_vector_type(8)));
typedef float  f32x4  __attribute__((ext_vector_type(4)));
using u16 = unsigned short;

__device__ __forceinline__ u16 bfbits(float f) {
  __bf16 h = (__bf16)f;
  union { __bf16 h; u16 u; } c; c.h = h;
  return c.u;
}
__device__ __forceinline__ float lopart(float f) {
  __bf16 h = (__bf16)f;
  return f - (float)h;
}

__device__ __forceinline__ void gload_lds16(const void* g, void* l) {
  const __attribute__((address_space(1))) unsigned* gp =
      (const __attribute__((address_space(1))) unsigned*)(unsigned long long)(uintptr_t)g;
  __attribute__((address_space(3))) unsigned* lp =
      (__attribute__((address_space(3))) unsigned*)(unsigned)(uintptr_t)l;
  __builtin_amdgcn_global_load_lds(gp, lp, 16, 0, 0);
}

#define MFMA16 __builtin_amdgcn_mfma_f32_16x16x32_bf16

// ------- Kernel 1: W_aug = [W_base | Bflat] bf16  +  Ms_pre emit -------
__global__ __launch_bounds__(256) void build_waug(const float* __restrict__ Wb,
                                                  const float* __restrict__ Bm,
                                                  const float* __restrict__ Wr,
                                                  const float* __restrict__ Amat,
                                                  u16* __restrict__ Wa,
                                                  u16* __restrict__ Msp) {
  const int bidx = blockIdx.x;
  const int tid = threadIdx.x;
  if (bidx < N_OUT) {
    const int d = bidx;
#pragma unroll
    for (int it = 0; it < 5; ++it) {
      int j = tid + it * 256;
      int kcol = j * 4;
      float4 v;
      if (kcol < K_IN) {
        v = *(const float4*)(Wb + (size_t)d * K_IN + kcol);
      } else {
        int kk = kcol - K_IN;
        int n = kk >> 6, r = kk & 63;
        v = *(const float4*)(Bm + ((size_t)n * N_OUT + d) * NRES + r);
      }
      ushort4 o;
      o.x = bfbits(v.x); o.y = bfbits(v.y); o.z = bfbits(v.z); o.w = bfbits(v.w);
      *(ushort4*)(Wa + (size_t)d * K_TOT + kcol) = o;
    }
  } else {
    const int row = bidx - N_OUT;           // 0..95
    const float* src = (row < 16) ? (Wr + (size_t)row * K_IN)
                     : (row < 80) ? (Amat + (size_t)(row - 16) * K_IN)
                                  : (Wr + (size_t)(row - 80) * K_IN);
    const bool lo = (row >= 80);
#pragma unroll
    for (int it = 0; it < 2; ++it) {
      int gi = tid + it * 256;              // granule 0..511
      int col = gi * 8;
      float4 a = *(const float4*)(src + col);
      float4 b = *(const float4*)(src + col + 4);
      float v0 = a.x, v1 = a.y, v2 = a.z, v3 = a.w;
      float v4 = b.x, v5 = b.y, v6 = b.z, v7 = b.w;
      if (lo) { v0 = lopart(v0); v1 = lopart(v1); v2 = lopart(v2); v3 = lopart(v3);
                v4 = lopart(v4); v5 = lopart(v5); v6 = lopart(v6); v7 = lopart(v7); }
      ushort4 o0, o1;
      o0.x = bfbits(v0); o0.y = bfbits(v1); o0.z = bfbits(v2); o0.w = bfbits(v3);
      o1.x = bfbits(v4); o1.y = bfbits(v5); o1.z = bfbits(v6); o1.w = bfbits(v7);
      u16* dst = Msp + ((size_t)(((gi >> 3) * 96 + row) * 8 + ((gi & 7) ^ (row & 7)))) * 8;
      *(ushort4*)(dst) = o0;
      *(ushort4*)(dst + 4) = o1;
    }
  }
}

// ---- Kernel 2: MFMA prep, DMA-staged M (identical to r5) ----
#define PSTR 72
#define BUF_U16 10752

__global__ __launch_bounds__(256) void prep_tokens(const float* __restrict__ x,
                                                   const u16* __restrict__ Msp,
                                                   const int* __restrict__ topk_p,
                                                   u16* __restrict__ Xa) {
  __shared__ __align__(16) u16 smem[2 * BUF_U16];
  const int tid = threadIdx.x;
  const int w = tid >> 6, l = tid & 63;
  const int l15 = l & 15, l4 = l >> 4;
  const int rt = w >> 1, cg = w & 1;
  const int token0 = blockIdx.x * 32;

  f32x4 acc[3] = {};

#define STAGE_CHUNK(kc, buf) do {                                              \
    u16* xh_ = smem + (buf) * BUF_U16;                                         \
    u16* xl_ = xh_ + 32 * PSTR;                                                \
    u16* Ms_ = xl_ + 32 * PSTR;                                                \
    const int k0_ = (kc) * 64;                                                 \
    _Pragma("unroll")                                                          \
    for (int it = 0; it < 3; ++it) {                                           \
      gload_lds16(Msp + (size_t)(kc) * 6144 + (size_t)(it * 256 + tid) * 8,    \
                  Ms_ + it * 2048 + w * 512);                                  \
    }                                                                          \
    _Pragma("unroll")                                                          \
    for (int it = 0; it < 2; ++it) {                                           \
      int i_ = tid + it * 256;                                                 \
      int row_ = i_ >> 4, c4_ = (i_ & 15) * 4;                                 \
      float4 v_ = *(const float4*)(x + (size_t)(token0 + row_) * K_IN + k0_ + c4_); \
      ushort4 h_;                                                              \
      h_.x = bfbits(v_.x); h_.y = bfbits(v_.y);                                \
      h_.z = bfbits(v_.z); h_.w = bfbits(v_.w);                                \
      ushort4 lo_;                                                             \
      lo_.x = bfbits(lopart(v_.x)); lo_.y = bfbits(lopart(v_.y));              \
      lo_.z = bfbits(lopart(v_.z)); lo_.w = bfbits(lopart(v_.w));              \
      *(ushort4*)&xh_[row_ * PSTR + c4_] = h_;                                 \
      *(ushort4*)&xl_[row_ * PSTR + c4_] = lo_;                                \
      *(ushort4*)(Xa + (size_t)(token0 + row_) * K_TOT + k0_ + c4_) = h_;      \
    }                                                                          \
  } while (0)

#define MS_FRAG(Ms_, tb, ks) \
  (*(const bf16x8*)&(Ms_)[(size_t)((((tb) * 16 + l15) * 8 + (((ks) * 4 + l4) ^ (l15 & 7)))) * 8])

  STAGE_CHUNK(0, 0);
  __syncthreads();

  for (int kc = 0; kc < NCH; ++kc) {
    const int cur = kc & 1;
    if (kc + 1 < NCH) {
      if ((kc + 1) & 1) STAGE_CHUNK(kc + 1, 1);
      else              STAGE_CHUNK(kc + 1, 0);
    }
    {
      const u16* xh_ = smem + cur * BUF_U16;
      const u16* xl_ = xh_ + 32 * PSTR;
      const u16* Ms_ = xl_ + 32 * PSTR;
      const int arow = (rt * 16 + l15) * PSTR;
#pragma unroll
      for (int ks = 0; ks < 2; ++ks) {
        const int fo = ks * 32 + l4 * 8;
        const bf16x8 ah = *(const bf16x8*)&xh_[arow + fo];
        if (cg == 0) {
          const bf16x8 al = *(const bf16x8*)&xl_[arow + fo];
          const bf16x8 b0 = MS_FRAG(Ms_, 0, ks);
          const bf16x8 b1 = MS_FRAG(Ms_, 1, ks);
          const bf16x8 b5 = MS_FRAG(Ms_, 5, ks);
          acc[0] = MFMA16(ah, b0, acc[0], 0, 0, 0);
          acc[0] = MFMA16(al, b0, acc[0], 0, 0, 0);
          acc[0] = MFMA16(ah, b5, acc[0], 0, 0, 0);
          acc[1] = MFMA16(ah, b1, acc[1], 0, 0, 0);
        } else {
          const bf16x8 b2 = MS_FRAG(Ms_, 2, ks);
          const bf16x8 b3 = MS_FRAG(Ms_, 3, ks);
          const bf16x8 b4 = MS_FRAG(Ms_, 4, ks);
          acc[0] = MFMA16(ah, b2, acc[0], 0, 0, 0);
          acc[1] = MFMA16(ah, b3, acc[1], 0, 0, 0);
          acc[2] = MFMA16(ah, b4, acc[2], 0, 0, 0);
        }
      }
    }
    __syncthreads();
  }

  float* arr  = (float*)smem;                       // [32][80]
  float* wexp = (float*)((char*)smem + 10240);      // [32][16]
  {
    const int row0 = rt * 16 + l4 * 4;
    if (cg == 0) {
#pragma unroll
      for (int ct = 0; ct < 2; ++ct)
#pragma unroll
        for (int j = 0; j < 4; ++j)
          arr[(row0 + j) * 80 + ct * 16 + l15] = acc[ct][j];
    } else {
#pragma unroll
      for (int ct = 0; ct < 3; ++ct)
#pragma unroll
        for (int j = 0; j < 4; ++j)
          arr[(row0 + j) * 80 + 32 + ct * 16 + l15] = acc[ct][j];
    }
  }
  __syncthreads();

  if (tid < 32) {
    const int tt = tid;
    const int k = *topk_p;
    float p[16];
    float mx = arr[tt * 80 + 0];
#pragma unroll
    for (int e = 1; e < 16; ++e) mx = fmaxf(mx, arr[tt * 80 + e]);
    float Z = 0.f;
#pragma unroll
    for (int e = 0; e < 16; ++e) { p[e] = expf(arr[tt * 80 + e] - mx); Z += p[e]; }
    const float invZ = 1.f / Z;
#pragma unroll
    for (int e = 0; e < 16; ++e) p[e] *= invZ;
    float wv[16];
    if (k <= 0 || k >= NEXP) {
#pragma unroll
      for (int e = 0; e < 16; ++e) wv[e] = p[e];
    } else {
      unsigned um = 0; float ssum = 0.f;
      for (int kk = 0; kk < k; ++kk) {
        int best = 0; float bv = -1.f;
#pragma unroll
        for (int e = 0; e < 16; ++e)
          if (!((um >> e) & 1u) && p[e] > bv) { bv = p[e]; best = e; }
        um |= 1u << best; ssum += bv;
      }
      const float inv = 1.f / (ssum + 1e-6f);
#pragma unroll
      for (int e = 0; e < 16; ++e) wv[e] = ((um >> e) & 1u) ? p[e] * inv : 0.f;
    }
#pragma unroll
    for (int e = 0; e < 16; ++e) wexp[tt * 16 + e] = wv[e];
  }
  __syncthreads();

#pragma unroll
  for (int it = 0; it < 16; ++it) {
    int idx = tid + it * 256;
    int tt = idx >> 7, c8 = idx & 127;
    int n = c8 >> 3, r0 = (c8 & 7) * 8;
    const float wv = wexp[tt * 16 + n];
    const float* hb = &arr[tt * 80 + 16 + r0];
    ushort4 lo, hi;
    lo.x = bfbits(wv * hb[0]); lo.y = bfbits(wv * hb[1]);
    lo.z = bfbits(wv * hb[2]); lo.w = bfbits(wv * hb[3]);
    hi.x = bfbits(wv * hb[4]); hi.y = bfbits(wv * hb[5]);
    hi.z = bfbits(wv * hb[6]); hi.w = bfbits(wv * hb[7]);
    u16* dst = Xa + (size_t)(token0 + tt) * K_TOT + K_IN + c8 * 8;
    *(ushort4*)(dst) = lo;
    *(ushort4*)(dst + 4) = hi;
  }
}

// ------ Kernel 3 (r7): 256^2 8-phase bf16 GEMM, 2 K-tiles per iteration ------
// 16x16x32 fragments (known-correct). Buffer parity compile-time via DO_TILE.
// LDS (u16): buf b*32768 ; A +0 / B +16384 ; half +8192 ; row*64.
#define PHASE_BAR() do {                      \
  __builtin_amdgcn_sched_barrier(0);          \
  __builtin_amdgcn_s_barrier();               \
  __builtin_amdgcn_sched_barrier(0);          \
} while (0)

#define LGKM0() do {                          \
  asm volatile("s_waitcnt lgkmcnt(0)");       \
  __builtin_amdgcn_sched_barrier(0);          \
} while (0)

__global__ __launch_bounds__(512, 2) void gemm_aug(const u16* __restrict__ Xa,
                                                   const u16* __restrict__ Wa,
                                                   const float* __restrict__ bias,
                                                   float* __restrict__ out) {
  extern __shared__ u16 lds[];
  const int tid = threadIdx.x;
  const int w = tid >> 6, l = tid & 63;
  const int bid = blockIdx.x;
  const int wg = (bid & 7) * 64 + (bid >> 3);     // T1: XCD-bijective (512%8==0)
  const int bm = wg >> 4, bn = wg & 15;
  const int wm = w >> 2, wn = w & 3;

  const int srow = w * 8 + (l >> 3);
  const int gsw = ((l & 7) ^ (l >> 3)) * 8;       // pre-swizzled global granule
  const u16* sA = Xa + (size_t)(bm * 256 + srow) * K_TOT + gsw;
  const u16* sB = Wa + (size_t)(bn * 256 + srow) * K_TOT + gsw;
  const int stq = w * 512;

  const int arow = (l & 15) * 64;
  const int c0 = (((l >> 4) + 0) ^ (l & 7)) * 8;
  const int c1 = (((l >> 4) + 4) ^ (l & 7)) * 8;

  f32x4 acc[8][4] = {};

#define STAGE_A2(tile, half, bufc) do {                                        \
    const u16* s_ = sA + (size_t)(half) * 128 * K_TOT + (size_t)(tile) * 64;   \
    const int d_ = (bufc) * 32768 + (half) * 8192 + stq;                       \
    gload_lds16(s_, &lds[d_]);                                                 \
    gload_lds16(s_ + (size_t)64 * K_TOT, &lds[d_ + 4096]);                     \
  } while (0)
#define STAGE_B2(tile, half, bufc) do {                                        \
    const u16* s_ = sB + (size_t)(half) * 128 * K_TOT + (size_t)(tile) * 64;   \
    const int d_ = (bufc) * 32768 + 16384 + (half) * 8192 + stq;               \
    gload_lds16(s_, &lds[d_]);                                                 \
    gload_lds16(s_ + (size_t)64 * K_TOT, &lds[d_ + 4096]);                     \
  } while (0)

  // prologue: tile0 full + tile1 {B0,B1,A0}; wait tile0 landed
  STAGE_B2(0, 0, 0); STAGE_B2(0, 1, 0); STAGE_A2(0, 0, 0); STAGE_A2(0, 1, 0);
  STAGE_B2(1, 0, 1); STAGE_B2(1, 1, 1); STAGE_A2(1, 0, 1);
  __builtin_amdgcn_sched_barrier(0);
  asm volatile("s_waitcnt vmcnt(6)");
  PHASE_BAR();

#define DO_TILE(TT, BUFC) do {                                                 \
    const int aoff_ = (BUFC) * 32768 + wm * 8192;                              \
    const int boff_ = (BUFC) * 32768 + 16384 + (wn >> 1) * 8192 + (wn & 1) * 4096; \
    bf16x8 af[4][2], b0f[2][2], b1f[2][2];                                     \
    /* P1: read A-mh0 (8) + B-nh0 (4); stage (TT+1).A1; MFMA quad (0,0) */     \
    _Pragma("unroll")                                                          \
    for (int m = 0; m < 4; ++m) {                                              \
      af[m][0] = *(const bf16x8*)&lds[aoff_ + m * 1024 + arow + c0];           \
      af[m][1] = *(const bf16x8*)&lds[aoff_ + m * 1024 + arow + c1];           \
    }                                                                          \
    _Pragma("unroll")                                                          \
    for (int n = 0; n < 2; ++n) {                                              \
      b0f[n][0] = *(const bf16x8*)&lds[boff_ + n * 1024 + arow + c0];          \
      b0f[n][1] = *(const bf16x8*)&lds[boff_ + n * 1024 + arow + c1];          \
    }                                                                          \
    if ((TT) + 1 < NT) STAGE_A2((TT) + 1, 1, (BUFC) ^ 1);                      \
    asm volatile("s_waitcnt lgkmcnt(8)");                                      \
    PHASE_BAR(); LGKM0();                                                      \
    __builtin_amdgcn_s_setprio(1);                                             \
    _Pragma("unroll")                                                          \
    for (int m = 0; m < 4; ++m)                                                \
      _Pragma("unroll")                                                        \
      for (int n = 0; n < 2; ++n) {                                            \
        acc[m][n] = MFMA16(af[m][0], b0f[n][0], acc[m][n], 0, 0, 0);           \
        acc[m][n] = MFMA16(af[m][1], b0f[n][1], acc[m][n], 0, 0, 0);           \
      }                                                                        \
    __builtin_amdgcn_s_setprio(0);                                             \
    PHASE_BAR();                                                               \
    /* P2: read B-nh1 (4); stage (TT+2).B0; MFMA quad (0,1) */                 \
    _Pragma("unroll")                                                          \
    for (int n = 0; n < 2; ++n) {                                              \
      b1f[n][0] = *(const bf16x8*)&lds[boff_ + (n + 2) * 1024 + arow + c0];    \
      b1f[n][1] = *(const bf16x8*)&lds[boff_ + (n + 2) * 1024 + arow + c1];    \
    }                                                                          \
    if ((TT) + 2 < NT) STAGE_B2((TT) + 2, 0, (BUFC));                          \
    PHASE_BAR(); LGKM0();                                                      \
    __builtin_amdgcn_s_setprio(1);                                             \
    _Pragma("unroll")                                                          \
    for (int m = 0; m < 4; ++m)                                                \
      _Pragma("unroll")                                                        \
      for (int n = 0; n < 2; ++n) {                                            \
        acc[m][n + 2] = MFMA16(af[m][0], b1f[n][0], acc[m][n + 2], 0, 0, 0);   \
        acc[m][n + 2] = MFMA16(af[m][1], b1f[n][1], acc[m][n + 2], 0, 0, 0);   \
      }                                                                        \
    __builtin_amdgcn_s_setprio(0);                                             \
    PHASE_BAR();                                                               \
    /* P3: read A-mh1 (8); stage (TT+2).B1; MFMA quad (1,1) */                 \
    _Pragma("unroll")                                                          \
    for (int m = 0; m < 4; ++m) {                                              \
      af[m][0] = *(const bf16x8*)&lds[aoff_ + 4096 + m * 1024 + arow + c0];    \
      af[m][1] = *(const bf16x8*)&lds[aoff_ + 4096 + m * 1024 + arow + c1];    \
    }                                                                          \
    if ((TT) + 2 < NT) STAGE_B2((TT) + 2, 1, (BUFC));                          \
    PHASE_BAR(); LGKM0();                                                      \
    __builtin_amdgcn_s_setprio(1);                                             \
    _Pragma("unroll")                                                          \
    for (int m = 0; m < 4; ++m)                                                \
      _Pragma("unroll")                                                        \
      for (int n = 0; n < 2; ++n) {                                            \
        acc[m + 4][n + 2] = MFMA16(af[m][0], b1f[n][0], acc[m + 4][n + 2], 0, 0, 0); \
        acc[m + 4][n + 2] = MFMA16(af[m][1], b1f[n][1], acc[m + 4][n + 2], 0, 0, 0); \
      }                                                                        \
    __builtin_amdgcn_s_setprio(0);                                             \
    PHASE_BAR();                                                               \
    /* P4: no reads (reuse af mh1, b0f); stage (TT+2).A0; boundary vmcnt */    \
    if ((TT) + 2 < NT) {                                                       \
      STAGE_A2((TT) + 2, 0, (BUFC));                                           \
      __builtin_amdgcn_sched_barrier(0);                                       \
      asm volatile("s_waitcnt vmcnt(6)");                                      \
    } else {                                                                   \
      asm volatile("s_waitcnt vmcnt(0)");                                      \
    }                                                                          \
    PHASE_BAR(); LGKM0();                                                      \
    __builtin_amdgcn_s_setprio(1);                                             \
    _Pragma("unroll")                                                          \
    for (int m = 0; m < 4; ++m)                                                \
      _Pragma("unroll")                                                        \
      for (int n = 0; n < 2; ++n) {                                            \
        acc[m + 4][n] = MFMA16(af[m][0], b0f[n][0], acc[m + 4][n], 0, 0, 0);   \
        acc[m + 4][n] = MFMA16(af[m][1], b0f[n][1], acc[m + 4][n], 0, 0, 0);   \
      }                                                                        \
    __builtin_amdgcn_s_setprio(0);                                             \
    PHASE_BAR();                                                               \
  } while (0)

  for (int t = 0; t < NT; t += 2) {
    DO_TILE(t, 0);
    DO_TILE(t + 1, 1);
  }

  // ---- epilogue: C/D layout col=lane&15, row=(lane>>4)*4+reg ----
  const int colBase = bn * 256 + wn * 64 + (l & 15);
  float bv[4];
#pragma unroll
  for (int n = 0; n < 4; ++n) bv[n] = bias[colBase + n * 16];
#pragma unroll
  for (int mi = 0; mi < 8; ++mi) {
    const int row = bm * 256 + wm * 128 + mi * 16 + (l >> 4) * 4;
#pragma unroll
    for (int j = 0; j < 4; ++j) {
      float* orow = out + (size_t)(row + j) * N_OUT + colBase;
#pragma unroll
      for (int n = 0; n < 4; ++n) orow[n * 16] = acc[mi][n][j] + bv[n];
    }
  }
}

extern "C" void kernel_launch(void* const* d_in, const int* in_sizes, int n_in,
                              void* d_out, int out_size, void* d_ws, size_t ws_size,
                              hipStream_t stream) {
  const float* x  = (const float*)d_in[0];
  const float* Wb = (const float*)d_in[1];
  const float* bb = (const float*)d_in[2];
  const float* Am = (const float*)d_in[3];
  const float* Bm = (const float*)d_in[4];
  const float* Wr = (const float*)d_in[5];
  const int* topk = (const int*)d_in[6];
  float* out = (float*)d_out;

  u16* Xa  = (u16*)d_ws;                          // 8192*5120 bf16
  u16* Wa  = Xa + (size_t)M_TOT * K_TOT;          // 4096*5120 bf16
  u16* Msp = Wa + (size_t)N_OUT * K_TOT;          // 64*96*64 bf16 (786 KB)

  (void)hipFuncSetAttribute((const void*)gemm_aug,
                            hipFuncAttributeMaxDynamicSharedMemorySize, 131072);

  hipLaunchKernelGGL(build_waug,  dim3(N_OUT + 96), dim3(256), 0, stream,
                     Wb, Bm, Wr, Am, Wa, Msp);
  hipLaunchKernelGGL(prep_tokens, dim3(M_TOT / 32), dim3(256), 0, stream,
                     x, Msp, topk, Xa);
  hipLaunchKernelGGL(gemm_aug,    dim3(512),        dim3(512), 131072, stream,
                     Xa, Wa, bb, out);
}

// Round 8
// 369.726 us; speedup vs baseline: 5.7445x; 1.0481x over previous
//
#include <hip/hip_runtime.h>
#include <hip/hip_bf16.h>
#include <cstdint>
#include <cmath>

// ResMoELoRALinear fused as ONE bf16 GEMM with augmented K:
//   out[8192,4096] = [x_bf16 | P] (8192x5120) @ [W_base | Bflat]^T (4096x5120) + b_base
// r8: gemm K-loop moved to ONE barrier per phase (cross-wave stagger so the
// LDS-read pipe overlaps the MFMA pipe across waves; r7 profile showed the
// two pipes fully serialized: 2480 MFMA + 2300 LDS cyc/tile = observed 4500).
// Staging remapped so every stage overwrites a region last-read >=2 phases
// earlier (formal happens-before safety: stage(p) issue > BAR(p-1) > peer
// lgkm-wait(p-2) > peer reads returned). Barriers 8->4 per K-tile.
// prep/build identical to r5.

#define M_TOT 8192
#define N_OUT 4096
#define K_IN  4096
#define K_TOT 5120
#define NEXP  16
#define NRES  64
#define NT    (K_TOT / 64)   // 80 K-tiles
#define NCH   (K_IN / 64)    // 64 prep chunks

typedef __bf16 bf16x8 __attribute__((ext_vector_type(8)));
typedef float  f32x4  __attribute__((ext_vector_type(4)));
using u16 = unsigned short;

__device__ __forceinline__ u16 bfbits(float f) {
  __bf16 h = (__bf16)f;
  union { __bf16 h; u16 u; } c; c.h = h;
  return c.u;
}
__device__ __forceinline__ float lopart(float f) {
  __bf16 h = (__bf16)f;
  return f - (float)h;
}

__device__ __forceinline__ void gload_lds16(const void* g, void* l) {
  const __attribute__((address_space(1))) unsigned* gp =
      (const __attribute__((address_space(1))) unsigned*)(unsigned long long)(uintptr_t)g;
  __attribute__((address_space(3))) unsigned* lp =
      (__attribute__((address_space(3))) unsigned*)(unsigned)(uintptr_t)l;
  __builtin_amdgcn_global_load_lds(gp, lp, 16, 0, 0);
}

#define MFMA16 __builtin_amdgcn_mfma_f32_16x16x32_bf16

// ------- Kernel 1: W_aug = [W_base | Bflat] bf16  +  Ms_pre emit -------
__global__ __launch_bounds__(256) void build_waug(const float* __restrict__ Wb,
                                                  const float* __restrict__ Bm,
                                                  const float* __restrict__ Wr,
                                                  const float* __restrict__ Amat,
                                                  u16* __restrict__ Wa,
                                                  u16* __restrict__ Msp) {
  const int bidx = blockIdx.x;
  const int tid = threadIdx.x;
  if (bidx < N_OUT) {
    const int d = bidx;
#pragma unroll
    for (int it = 0; it < 5; ++it) {
      int j = tid + it * 256;
      int kcol = j * 4;
      float4 v;
      if (kcol < K_IN) {
        v = *(const float4*)(Wb + (size_t)d * K_IN + kcol);
      } else {
        int kk = kcol - K_IN;
        int n = kk >> 6, r = kk & 63;
        v = *(const float4*)(Bm + ((size_t)n * N_OUT + d) * NRES + r);
      }
      ushort4 o;
      o.x = bfbits(v.x); o.y = bfbits(v.y); o.z = bfbits(v.z); o.w = bfbits(v.w);
      *(ushort4*)(Wa + (size_t)d * K_TOT + kcol) = o;
    }
  } else {
    const int row = bidx - N_OUT;           // 0..95
    const float* src = (row < 16) ? (Wr + (size_t)row * K_IN)
                     : (row < 80) ? (Amat + (size_t)(row - 16) * K_IN)
                                  : (Wr + (size_t)(row - 80) * K_IN);
    const bool lo = (row >= 80);
#pragma unroll
    for (int it = 0; it < 2; ++it) {
      int gi = tid + it * 256;              // granule 0..511
      int col = gi * 8;
      float4 a = *(const float4*)(src + col);
      float4 b = *(const float4*)(src + col + 4);
      float v0 = a.x, v1 = a.y, v2 = a.z, v3 = a.w;
      float v4 = b.x, v5 = b.y, v6 = b.z, v7 = b.w;
      if (lo) { v0 = lopart(v0); v1 = lopart(v1); v2 = lopart(v2); v3 = lopart(v3);
                v4 = lopart(v4); v5 = lopart(v5); v6 = lopart(v6); v7 = lopart(v7); }
      ushort4 o0, o1;
      o0.x = bfbits(v0); o0.y = bfbits(v1); o0.z = bfbits(v2); o0.w = bfbits(v3);
      o1.x = bfbits(v4); o1.y = bfbits(v5); o1.z = bfbits(v6); o1.w = bfbits(v7);
      u16* dst = Msp + ((size_t)(((gi >> 3) * 96 + row) * 8 + ((gi & 7) ^ (row & 7)))) * 8;
      *(ushort4*)(dst) = o0;
      *(ushort4*)(dst + 4) = o1;
    }
  }
}

// ---- Kernel 2: MFMA prep, DMA-staged M (identical to r5) ----
#define PSTR 72
#define BUF_U16 10752

__global__ __launch_bounds__(256) void prep_tokens(const float* __restrict__ x,
                                                   const u16* __restrict__ Msp,
                                                   const int* __restrict__ topk_p,
                                                   u16* __restrict__ Xa) {
  __shared__ __align__(16) u16 smem[2 * BUF_U16];
  const int tid = threadIdx.x;
  const int w = tid >> 6, l = tid & 63;
  const int l15 = l & 15, l4 = l >> 4;
  const int rt = w >> 1, cg = w & 1;
  const int token0 = blockIdx.x * 32;

  f32x4 acc[3] = {};

#define STAGE_CHUNK(kc, buf) do {                                              \
    u16* xh_ = smem + (buf) * BUF_U16;                                         \
    u16* xl_ = xh_ + 32 * PSTR;                                                \
    u16* Ms_ = xl_ + 32 * PSTR;                                                \
    const int k0_ = (kc) * 64;                                                 \
    _Pragma("unroll")                                                          \
    for (int it = 0; it < 3; ++it) {                                           \
      gload_lds16(Msp + (size_t)(kc) * 6144 + (size_t)(it * 256 + tid) * 8,    \
                  Ms_ + it * 2048 + w * 512);                                  \
    }                                                                          \
    _Pragma("unroll")                                                          \
    for (int it = 0; it < 2; ++it) {                                           \
      int i_ = tid + it * 256;                                                 \
      int row_ = i_ >> 4, c4_ = (i_ & 15) * 4;                                 \
      float4 v_ = *(const float4*)(x + (size_t)(token0 + row_) * K_IN + k0_ + c4_); \
      ushort4 h_;                                                              \
      h_.x = bfbits(v_.x); h_.y = bfbits(v_.y);                                \
      h_.z = bfbits(v_.z); h_.w = bfbits(v_.w);                                \
      ushort4 lo_;                                                             \
      lo_.x = bfbits(lopart(v_.x)); lo_.y = bfbits(lopart(v_.y));              \
      lo_.z = bfbits(lopart(v_.z)); lo_.w = bfbits(lopart(v_.w));              \
      *(ushort4*)&xh_[row_ * PSTR + c4_] = h_;                                 \
      *(ushort4*)&xl_[row_ * PSTR + c4_] = lo_;                                \
      *(ushort4*)(Xa + (size_t)(token0 + row_) * K_TOT + k0_ + c4_) = h_;      \
    }                                                                          \
  } while (0)

#define MS_FRAG(Ms_, tb, ks) \
  (*(const bf16x8*)&(Ms_)[(size_t)((((tb) * 16 + l15) * 8 + (((ks) * 4 + l4) ^ (l15 & 7)))) * 8])

  STAGE_CHUNK(0, 0);
  __syncthreads();

  for (int kc = 0; kc < NCH; ++kc) {
    const int cur = kc & 1;
    if (kc + 1 < NCH) {
      if ((kc + 1) & 1) STAGE_CHUNK(kc + 1, 1);
      else              STAGE_CHUNK(kc + 1, 0);
    }
    {
      const u16* xh_ = smem + cur * BUF_U16;
      const u16* xl_ = xh_ + 32 * PSTR;
      const u16* Ms_ = xl_ + 32 * PSTR;
      const int arow = (rt * 16 + l15) * PSTR;
#pragma unroll
      for (int ks = 0; ks < 2; ++ks) {
        const int fo = ks * 32 + l4 * 8;
        const bf16x8 ah = *(const bf16x8*)&xh_[arow + fo];
        if (cg == 0) {
          const bf16x8 al = *(const bf16x8*)&xl_[arow + fo];
          const bf16x8 b0 = MS_FRAG(Ms_, 0, ks);
          const bf16x8 b1 = MS_FRAG(Ms_, 1, ks);
          const bf16x8 b5 = MS_FRAG(Ms_, 5, ks);
          acc[0] = MFMA16(ah, b0, acc[0], 0, 0, 0);
          acc[0] = MFMA16(al, b0, acc[0], 0, 0, 0);
          acc[0] = MFMA16(ah, b5, acc[0], 0, 0, 0);
          acc[1] = MFMA16(ah, b1, acc[1], 0, 0, 0);
        } else {
          const bf16x8 b2 = MS_FRAG(Ms_, 2, ks);
          const bf16x8 b3 = MS_FRAG(Ms_, 3, ks);
          const bf16x8 b4 = MS_FRAG(Ms_, 4, ks);
          acc[0] = MFMA16(ah, b2, acc[0], 0, 0, 0);
          acc[1] = MFMA16(ah, b3, acc[1], 0, 0, 0);
          acc[2] = MFMA16(ah, b4, acc[2], 0, 0, 0);
        }
      }
    }
    __syncthreads();
  }

  float* arr  = (float*)smem;                       // [32][80]
  float* wexp = (float*)((char*)smem + 10240);      // [32][16]
  {
    const int row0 = rt * 16 + l4 * 4;
    if (cg == 0) {
#pragma unroll
      for (int ct = 0; ct < 2; ++ct)
#pragma unroll
        for (int j = 0; j < 4; ++j)
          arr[(row0 + j) * 80 + ct * 16 + l15] = acc[ct][j];
    } else {
#pragma unroll
      for (int ct = 0; ct < 3; ++ct)
#pragma unroll
        for (int j = 0; j < 4; ++j)
          arr[(row0 + j) * 80 + 32 + ct * 16 + l15] = acc[ct][j];
    }
  }
  __syncthreads();

  if (tid < 32) {
    const int tt = tid;
    const int k = *topk_p;
    float p[16];
    float mx = arr[tt * 80 + 0];
#pragma unroll
    for (int e = 1; e < 16; ++e) mx = fmaxf(mx, arr[tt * 80 + e]);
    float Z = 0.f;
#pragma unroll
    for (int e = 0; e < 16; ++e) { p[e] = expf(arr[tt * 80 + e] - mx); Z += p[e]; }
    const float invZ = 1.f / Z;
#pragma unroll
    for (int e = 0; e < 16; ++e) p[e] *= invZ;
    float wv[16];
    if (k <= 0 || k >= NEXP) {
#pragma unroll
      for (int e = 0; e < 16; ++e) wv[e] = p[e];
    } else {
      unsigned um = 0; float ssum = 0.f;
      for (int kk = 0; kk < k; ++kk) {
        int best = 0; float bv = -1.f;
#pragma unroll
        for (int e = 0; e < 16; ++e)
          if (!((um >> e) & 1u) && p[e] > bv) { bv = p[e]; best = e; }
        um |= 1u << best; ssum += bv;
      }
      const float inv = 1.f / (ssum + 1e-6f);
#pragma unroll
      for (int e = 0; e < 16; ++e) wv[e] = ((um >> e) & 1u) ? p[e] * inv : 0.f;
    }
#pragma unroll
    for (int e = 0; e < 16; ++e) wexp[tt * 16 + e] = wv[e];
  }
  __syncthreads();

#pragma unroll
  for (int it = 0; it < 16; ++it) {
    int idx = tid + it * 256;
    int tt = idx >> 7, c8 = idx & 127;
    int n = c8 >> 3, r0 = (c8 & 7) * 8;
    const float wv = wexp[tt * 16 + n];
    const float* hb = &arr[tt * 80 + 16 + r0];
    ushort4 lo, hi;
    lo.x = bfbits(wv * hb[0]); lo.y = bfbits(wv * hb[1]);
    lo.z = bfbits(wv * hb[2]); lo.w = bfbits(wv * hb[3]);
    hi.x = bfbits(wv * hb[4]); hi.y = bfbits(wv * hb[5]);
    hi.z = bfbits(wv * hb[6]); hi.w = bfbits(wv * hb[7]);
    u16* dst = Xa + (size_t)(token0 + tt) * K_TOT + K_IN + c8 * 8;
    *(ushort4*)(dst) = lo;
    *(ushort4*)(dst + 4) = hi;
  }
}

// ------ Kernel 3 (r8): 256^2 GEMM, ONE barrier per phase, 2-phase-gap staging ------
// 16x16x32 fragments. LDS (u16): buf b*32768 ; A +0 / B +16384 ; half +8192 ; row*64.
// Per phase: {ds_reads ; stage ; BAR ; lgkm0 ; setprio MFMA setprio}. No trailing BAR.
// Stage map: P1 A1(t+1)->buf^1 ; P2 none ; P3 B0(t+2) ; P4 B1(t+2)+A0(t+2)+vmcnt(6).
#define PHASE_BAR() do {                      \
  __builtin_amdgcn_sched_barrier(0);          \
  __builtin_amdgcn_s_barrier();               \
  __builtin_amdgcn_sched_barrier(0);          \
} while (0)

#define LGKM0() do {                          \
  asm volatile("s_waitcnt lgkmcnt(0)");       \
  __builtin_amdgcn_sched_barrier(0);          \
} while (0)

__global__ __launch_bounds__(512, 2) void gemm_aug(const u16* __restrict__ Xa,
                                                   const u16* __restrict__ Wa,
                                                   const float* __restrict__ bias,
                                                   float* __restrict__ out) {
  extern __shared__ u16 lds[];
  const int tid = threadIdx.x;
  const int w = tid >> 6, l = tid & 63;
  const int bid = blockIdx.x;
  const int wg = (bid & 7) * 64 + (bid >> 3);     // T1: XCD-bijective (512%8==0)
  const int bm = wg >> 4, bn = wg & 15;
  const int wm = w >> 2, wn = w & 3;

  const int srow = w * 8 + (l >> 3);
  const int gsw = ((l & 7) ^ (l >> 3)) * 8;       // pre-swizzled global granule
  const u16* sA = Xa + (size_t)(bm * 256 + srow) * K_TOT + gsw;
  const u16* sB = Wa + (size_t)(bn * 256 + srow) * K_TOT + gsw;
  const int stq = w * 512;

  const int arow = (l & 15) * 64;
  const int c0 = (((l >> 4) + 0) ^ (l & 7)) * 8;
  const int c1 = (((l >> 4) + 4) ^ (l & 7)) * 8;

  f32x4 acc[8][4] = {};

#define STAGE_A2(tile, half, bufc) do {                                        \
    const u16* s_ = sA + (size_t)(half) * 128 * K_TOT + (size_t)(tile) * 64;   \
    const int d_ = (bufc) * 32768 + (half) * 8192 + stq;                       \
    gload_lds16(s_, &lds[d_]);                                                 \
    gload_lds16(s_ + (size_t)64 * K_TOT, &lds[d_ + 4096]);                     \
  } while (0)
#define STAGE_B2(tile, half, bufc) do {                                        \
    const u16* s_ = sB + (size_t)(half) * 128 * K_TOT + (size_t)(tile) * 64;   \
    const int d_ = (bufc) * 32768 + 16384 + (half) * 8192 + stq;               \
    gload_lds16(s_, &lds[d_]);                                                 \
    gload_lds16(s_ + (size_t)64 * K_TOT, &lds[d_ + 4096]);                     \
  } while (0)

  // prologue: tile0 full + tile1 {B0,B1,A0}; wait tile0 landed (vmcnt(6))
  STAGE_B2(0, 0, 0); STAGE_B2(0, 1, 0); STAGE_A2(0, 0, 0); STAGE_A2(0, 1, 0);
  STAGE_B2(1, 0, 1); STAGE_B2(1, 1, 1); STAGE_A2(1, 0, 1);
  __builtin_amdgcn_sched_barrier(0);
  asm volatile("s_waitcnt vmcnt(6)");
  PHASE_BAR();

#define DO_TILE(TT, BUFC) do {                                                 \
    const int aoff_ = (BUFC) * 32768 + wm * 8192;                              \
    const int boff_ = (BUFC) * 32768 + 16384 + (wn >> 1) * 8192 + (wn & 1) * 4096; \
    bf16x8 af[4][2], b0f[2][2], b1f[2][2];                                     \
    /* P1: reads af-mh0 (8) + b0f (4); stage A1(t+1)->buf^1; BAR; MFMA (0,0) */ \
    _Pragma("unroll")                                                          \
    for (int m = 0; m < 4; ++m) {                                              \
      af[m][0] = *(const bf16x8*)&lds[aoff_ + m * 1024 + arow + c0];           \
      af[m][1] = *(const bf16x8*)&lds[aoff_ + m * 1024 + arow + c1];           \
    }                                                                          \
    _Pragma("unroll")                                                          \
    for (int n = 0; n < 2; ++n) {                                              \
      b0f[n][0] = *(const bf16x8*)&lds[boff_ + n * 1024 + arow + c0];          \
      b0f[n][1] = *(const bf16x8*)&lds[boff_ + n * 1024 + arow + c1];          \
    }                                                                          \
    if ((TT) + 1 < NT) STAGE_A2((TT) + 1, 1, (BUFC) ^ 1);                      \
    PHASE_BAR(); LGKM0();                                                      \
    __builtin_amdgcn_s_setprio(1);                                             \
    _Pragma("unroll")                                                          \
    for (int m = 0; m < 4; ++m)                                                \
      _Pragma("unroll")                                                        \
      for (int n = 0; n < 2; ++n) {                                            \
        acc[m][n] = MFMA16(af[m][0], b0f[n][0], acc[m][n], 0, 0, 0);           \
        acc[m][n] = MFMA16(af[m][1], b0f[n][1], acc[m][n], 0, 0, 0);           \
      }                                                                        \
    __builtin_amdgcn_s_setprio(0);                                             \
    /* P2: reads b1f (4); no stage; BAR; MFMA (0,1) */                         \
    _Pragma("unroll")                                                          \
    for (int n = 0; n < 2; ++n) {                                              \
      b1f[n][0] = *(const bf16x8*)&lds[boff_ + (n + 2) * 1024 + arow + c0];    \
      b1f[n][1] = *(const bf16x8*)&lds[boff_ + (n + 2) * 1024 + arow + c1];    \
    }                                                                          \
    PHASE_BAR(); LGKM0();                                                      \
    __builtin_amdgcn_s_setprio(1);                                             \
    _Pragma("unroll")                                                          \
    for (int m = 0; m < 4; ++m)                                                \
      _Pragma("unroll")                                                        \
      for (int n = 0; n < 2; ++n) {                                            \
        acc[m][n + 2] = MFMA16(af[m][0], b1f[n][0], acc[m][n + 2], 0, 0, 0);   \
        acc[m][n + 2] = MFMA16(af[m][1], b1f[n][1], acc[m][n + 2], 0, 0, 0);   \
      }                                                                        \
    __builtin_amdgcn_s_setprio(0);                                             \
    /* P3: reads af-mh1 (8); stage B0(t+2); BAR; MFMA (1,1) */                 \
    _Pragma("unroll")                                                          \
    for (int m = 0; m < 4; ++m) {                                              \
      af[m][0] = *(const bf16x8*)&lds[aoff_ + 4096 + m * 1024 + arow + c0];    \
      af[m][1] = *(const bf16x8*)&lds[aoff_ + 4096 + m * 1024 + arow + c1];    \
    }                                                                          \
    if ((TT) + 2 < NT) STAGE_B2((TT) + 2, 0, (BUFC));                          \
    PHASE_BAR(); LGKM0();                                                      \
    __builtin_amdgcn_s_setprio(1);                                             \
    _Pragma("unroll")                                                          \
    for (int m = 0; m < 4; ++m)                                                \
      _Pragma("unroll")                                                        \
      for (int n = 0; n < 2; ++n) {                                            \
        acc[m + 4][n + 2] = MFMA16(af[m][0], b1f[n][0], acc[m + 4][n + 2], 0, 0, 0); \
        acc[m + 4][n + 2] = MFMA16(af[m][1], b1f[n][1], acc[m + 4][n + 2], 0, 0, 0); \
      }                                                                        \
    __builtin_amdgcn_s_setprio(0);                                             \
    /* P4: no reads; stage B1(t+2)+A0(t+2); vmcnt(6); BAR; MFMA (1,0) */       \
    if ((TT) + 2 < NT) {                                                       \
      STAGE_B2((TT) + 2, 1, (BUFC));                                           \
      STAGE_A2((TT) + 2, 0, (BUFC));                                           \
      __builtin_amdgcn_sched_barrier(0);                                       \
      asm volatile("s_waitcnt vmcnt(6)");                                      \
    } else {                                                                   \
      asm volatile("s_waitcnt vmcnt(0)");                                      \
    }                                                                          \
    PHASE_BAR();                                                               \
    __builtin_amdgcn_s_setprio(1);                                             \
    _Pragma("unroll")                                                          \
    for (int m = 0; m < 4; ++m)                                                \
      _Pragma("unroll")                                                        \
      for (int n = 0; n < 2; ++n) {                                            \
        acc[m + 4][n] = MFMA16(af[m][0], b0f[n][0], acc[m + 4][n], 0, 0, 0);   \
        acc[m + 4][n] = MFMA16(af[m][1], b0f[n][1], acc[m + 4][n], 0, 0, 0);   \
      }                                                                        \
    __builtin_amdgcn_s_setprio(0);                                             \
  } while (0)

  for (int t = 0; t < NT; t += 2) {
    DO_TILE(t, 0);
    DO_TILE(t + 1, 1);
  }

  // ---- epilogue: C/D layout col=lane&15, row=(lane>>4)*4+reg ----
  const int colBase = bn * 256 + wn * 64 + (l & 15);
  float bv[4];
#pragma unroll
  for (int n = 0; n < 4; ++n) bv[n] = bias[colBase + n * 16];
#pragma unroll
  for (int mi = 0; mi < 8; ++mi) {
    const int row = bm * 256 + wm * 128 + mi * 16 + (l >> 4) * 4;
#pragma unroll
    for (int j = 0; j < 4; ++j) {
      float* orow = out + (size_t)(row + j) * N_OUT + colBase;
#pragma unroll
      for (int n = 0; n < 4; ++n) orow[n * 16] = acc[mi][n][j] + bv[n];
    }
  }
}

extern "C" void kernel_launch(void* const* d_in, const int* in_sizes, int n_in,
                              void* d_out, int out_size, void* d_ws, size_t ws_size,
                              hipStream_t stream) {
  const float* x  = (const float*)d_in[0];
  const float* Wb = (const float*)d_in[1];
  const float* bb = (const float*)d_in[2];
  const float* Am = (const float*)d_in[3];
  const float* Bm = (const float*)d_in[4];
  const float* Wr = (const float*)d_in[5];
  const int* topk = (const int*)d_in[6];
  float* out = (float*)d_out;

  u16* Xa  = (u16*)d_ws;                          // 8192*5120 bf16
  u16* Wa  = Xa + (size_t)M_TOT * K_TOT;          // 4096*5120 bf16
  u16* Msp = Wa + (size_t)N_OUT * K_TOT;          // 64*96*64 bf16 (786 KB)

  (void)hipFuncSetAttribute((const void*)gemm_aug,
                            hipFuncAttributeMaxDynamicSharedMemorySize, 131072);

  hipLaunchKernelGGL(build_waug,  dim3(N_OUT + 96), dim3(256), 0, stream,
                     Wb, Bm, Wr, Am, Wa, Msp);
  hipLaunchKernelGGL(prep_tokens, dim3(M_TOT / 32), dim3(256), 0, stream,
                     x, Msp, topk, Xa);
  hipLaunchKernelGGL(gemm_aug,    dim3(512),        dim3(512), 131072, stream,
                     Xa, Wa, bb, out);
}

// Round 9
// 359.616 us; speedup vs baseline: 5.9060x; 1.0281x over previous
//
#include <hip/hip_runtime.h>
#include <hip/hip_bf16.h>
#include <cstdint>
#include <cmath>

// ResMoELoRALinear fused as ONE bf16 GEMM with augmented K:
//   out[8192,4096] = [x_bf16 | P] (8192x5120) @ [W_base | Bflat]^T (4096x5120) + b_base
// r9: dependency-aware fusion of the pre-GEMM stage. build_msp (96 blocks,
// ~5us) produces Msp only; then ONE fused kernel runs prep blocks (0-255,
// first) concurrently with the Wa bf16-conversion blocks (256-4351) — the
// Wa traffic hides under prep's compute. gemm_aug byte-identical to r8
// (control: 272us, MfmaUtil 56.6%, 1 block/CU structural).

#define M_TOT 8192
#define N_OUT 4096
#define K_IN  4096
#define K_TOT 5120
#define NEXP  16
#define NRES  64
#define NT    (K_TOT / 64)   // 80 K-tiles
#define NCH   (K_IN / 64)    // 64 prep chunks

typedef __bf16 bf16x8 __attribute__((ext_vector_type(8)));
typedef float  f32x4  __attribute__((ext_vector_type(4)));
using u16 = unsigned short;

__device__ __forceinline__ u16 bfbits(float f) {
  __bf16 h = (__bf16)f;
  union { __bf16 h; u16 u; } c; c.h = h;
  return c.u;
}
__device__ __forceinline__ float lopart(float f) {
  __bf16 h = (__bf16)f;
  return f - (float)h;
}

__device__ __forceinline__ void gload_lds16(const void* g, void* l) {
  const __attribute__((address_space(1))) unsigned* gp =
      (const __attribute__((address_space(1))) unsigned*)(unsigned long long)(uintptr_t)g;
  __attribute__((address_space(3))) unsigned* lp =
      (__attribute__((address_space(3))) unsigned*)(unsigned)(uintptr_t)l;
  __builtin_amdgcn_global_load_lds(gp, lp, 16, 0, 0);
}

#define MFMA16 __builtin_amdgcn_mfma_f32_16x16x32_bf16

// ------- Kernel 1: Msp emit only (96 blocks) -------
// Msp layout: [chunk 64][row 96][g 8][e 8] u16, stored granule g' = g^(row&7).
// rows 0-15 = WrHi, 16-79 = A, 80-95 = WrLo.
__global__ __launch_bounds__(256) void build_msp(const float* __restrict__ Wr,
                                                 const float* __restrict__ Amat,
                                                 u16* __restrict__ Msp) {
  const int row = blockIdx.x;               // 0..95
  const int tid = threadIdx.x;
  const float* src = (row < 16) ? (Wr + (size_t)row * K_IN)
                   : (row < 80) ? (Amat + (size_t)(row - 16) * K_IN)
                                : (Wr + (size_t)(row - 80) * K_IN);
  const bool lo = (row >= 80);
#pragma unroll
  for (int it = 0; it < 2; ++it) {
    int gi = tid + it * 256;                // granule 0..511
    int col = gi * 8;
    float4 a = *(const float4*)(src + col);
    float4 b = *(const float4*)(src + col + 4);
    float v0 = a.x, v1 = a.y, v2 = a.z, v3 = a.w;
    float v4 = b.x, v5 = b.y, v6 = b.z, v7 = b.w;
    if (lo) { v0 = lopart(v0); v1 = lopart(v1); v2 = lopart(v2); v3 = lopart(v3);
              v4 = lopart(v4); v5 = lopart(v5); v6 = lopart(v6); v7 = lopart(v7); }
    ushort4 o0, o1;
    o0.x = bfbits(v0); o0.y = bfbits(v1); o0.z = bfbits(v2); o0.w = bfbits(v3);
    o1.x = bfbits(v4); o1.y = bfbits(v5); o1.z = bfbits(v6); o1.w = bfbits(v7);
    u16* dst = Msp + ((size_t)(((gi >> 3) * 96 + row) * 8 + ((gi & 7) ^ (row & 7)))) * 8;
    *(ushort4*)(dst) = o0;
    *(ushort4*)(dst + 4) = o1;
  }
}

// ---- Kernel 2: FUSED prep (blocks 0-255) + Wa conversion (blocks 256-4351) ----
#define PSTR 72
#define BUF_U16 10752

__global__ __launch_bounds__(256) void prep_fused(const float* __restrict__ x,
                                                  const u16* __restrict__ Msp,
                                                  const int* __restrict__ topk_p,
                                                  const float* __restrict__ Wb,
                                                  const float* __restrict__ Bm,
                                                  u16* __restrict__ Xa,
                                                  u16* __restrict__ Wa) {
  __shared__ __align__(16) u16 smem[2 * BUF_U16];
  const int tid = threadIdx.x;

  if (blockIdx.x >= 256) {
    // ---- Wa conversion path: row d = blockIdx.x - 256 ----
    const int d = blockIdx.x - 256;
#pragma unroll
    for (int it = 0; it < 5; ++it) {
      int j = tid + it * 256;
      int kcol = j * 4;
      float4 v;
      if (kcol < K_IN) {
        v = *(const float4*)(Wb + (size_t)d * K_IN + kcol);
      } else {
        int kk = kcol - K_IN;
        int n = kk >> 6, r = kk & 63;
        v = *(const float4*)(Bm + ((size_t)n * N_OUT + d) * NRES + r);
      }
      ushort4 o;
      o.x = bfbits(v.x); o.y = bfbits(v.y); o.z = bfbits(v.z); o.w = bfbits(v.w);
      *(ushort4*)(Wa + (size_t)d * K_TOT + kcol) = o;
    }
    return;
  }

  // ---- prep path: 32 tokens/block, K-chunks of 64 (identical to r5 body) ----
  const int w = tid >> 6, l = tid & 63;
  const int l15 = l & 15, l4 = l >> 4;
  const int rt = w >> 1, cg = w & 1;
  const int token0 = blockIdx.x * 32;

  f32x4 acc[3] = {};

#define STAGE_CHUNK(kc, buf) do {                                              \
    u16* xh_ = smem + (buf) * BUF_U16;                                         \
    u16* xl_ = xh_ + 32 * PSTR;                                                \
    u16* Ms_ = xl_ + 32 * PSTR;                                                \
    const int k0_ = (kc) * 64;                                                 \
    _Pragma("unroll")                                                          \
    for (int it = 0; it < 3; ++it) {                                           \
      gload_lds16(Msp + (size_t)(kc) * 6144 + (size_t)(it * 256 + tid) * 8,    \
                  Ms_ + it * 2048 + w * 512);                                  \
    }                                                                          \
    _Pragma("unroll")                                                          \
    for (int it = 0; it < 2; ++it) {                                           \
      int i_ = tid + it * 256;                                                 \
      int row_ = i_ >> 4, c4_ = (i_ & 15) * 4;                                 \
      float4 v_ = *(const float4*)(x + (size_t)(token0 + row_) * K_IN + k0_ + c4_); \
      ushort4 h_;                                                              \
      h_.x = bfbits(v_.x); h_.y = bfbits(v_.y);                                \
      h_.z = bfbits(v_.z); h_.w = bfbits(v_.w);                                \
      ushort4 lo_;                                                             \
      lo_.x = bfbits(lopart(v_.x)); lo_.y = bfbits(lopart(v_.y));              \
      lo_.z = bfbits(lopart(v_.z)); lo_.w = bfbits(lopart(v_.w));              \
      *(ushort4*)&xh_[row_ * PSTR + c4_] = h_;                                 \
      *(ushort4*)&xl_[row_ * PSTR + c4_] = lo_;                                \
      *(ushort4*)(Xa + (size_t)(token0 + row_) * K_TOT + k0_ + c4_) = h_;      \
    }                                                                          \
  } while (0)

#define MS_FRAG(Ms_, tb, ks) \
  (*(const bf16x8*)&(Ms_)[(size_t)((((tb) * 16 + l15) * 8 + (((ks) * 4 + l4) ^ (l15 & 7)))) * 8])

  STAGE_CHUNK(0, 0);
  __syncthreads();

  for (int kc = 0; kc < NCH; ++kc) {
    const int cur = kc & 1;
    if (kc + 1 < NCH) {
      if ((kc + 1) & 1) STAGE_CHUNK(kc + 1, 1);
      else              STAGE_CHUNK(kc + 1, 0);
    }
    {
      const u16* xh_ = smem + cur * BUF_U16;
      const u16* xl_ = xh_ + 32 * PSTR;
      const u16* Ms_ = xl_ + 32 * PSTR;
      const int arow = (rt * 16 + l15) * PSTR;
#pragma unroll
      for (int ks = 0; ks < 2; ++ks) {
        const int fo = ks * 32 + l4 * 8;
        const bf16x8 ah = *(const bf16x8*)&xh_[arow + fo];
        if (cg == 0) {
          const bf16x8 al = *(const bf16x8*)&xl_[arow + fo];
          const bf16x8 b0 = MS_FRAG(Ms_, 0, ks);
          const bf16x8 b1 = MS_FRAG(Ms_, 1, ks);
          const bf16x8 b5 = MS_FRAG(Ms_, 5, ks);
          acc[0] = MFMA16(ah, b0, acc[0], 0, 0, 0);
          acc[0] = MFMA16(al, b0, acc[0], 0, 0, 0);
          acc[0] = MFMA16(ah, b5, acc[0], 0, 0, 0);
          acc[1] = MFMA16(ah, b1, acc[1], 0, 0, 0);
        } else {
          const bf16x8 b2 = MS_FRAG(Ms_, 2, ks);
          const bf16x8 b3 = MS_FRAG(Ms_, 3, ks);
          const bf16x8 b4 = MS_FRAG(Ms_, 4, ks);
          acc[0] = MFMA16(ah, b2, acc[0], 0, 0, 0);
          acc[1] = MFMA16(ah, b3, acc[1], 0, 0, 0);
          acc[2] = MFMA16(ah, b4, acc[2], 0, 0, 0);
        }
      }
    }
    __syncthreads();
  }

  float* arr  = (float*)smem;                       // [32][80]
  float* wexp = (float*)((char*)smem + 10240);      // [32][16]
  {
    const int row0 = rt * 16 + l4 * 4;
    if (cg == 0) {
#pragma unroll
      for (int ct = 0; ct < 2; ++ct)
#pragma unroll
        for (int j = 0; j < 4; ++j)
          arr[(row0 + j) * 80 + ct * 16 + l15] = acc[ct][j];
    } else {
#pragma unroll
      for (int ct = 0; ct < 3; ++ct)
#pragma unroll
        for (int j = 0; j < 4; ++j)
          arr[(row0 + j) * 80 + 32 + ct * 16 + l15] = acc[ct][j];
    }
  }
  __syncthreads();

  if (tid < 32) {
    const int tt = tid;
    const int k = *topk_p;
    float p[16];
    float mx = arr[tt * 80 + 0];
#pragma unroll
    for (int e = 1; e < 16; ++e) mx = fmaxf(mx, arr[tt * 80 + e]);
    float Z = 0.f;
#pragma unroll
    for (int e = 0; e < 16; ++e) { p[e] = expf(arr[tt * 80 + e] - mx); Z += p[e]; }
    const float invZ = 1.f / Z;
#pragma unroll
    for (int e = 0; e < 16; ++e) p[e] *= invZ;
    float wv[16];
    if (k <= 0 || k >= NEXP) {
#pragma unroll
      for (int e = 0; e < 16; ++e) wv[e] = p[e];
    } else {
      unsigned um = 0; float ssum = 0.f;
      for (int kk = 0; kk < k; ++kk) {
        int best = 0; float bv = -1.f;
#pragma unroll
        for (int e = 0; e < 16; ++e)
          if (!((um >> e) & 1u) && p[e] > bv) { bv = p[e]; best = e; }
        um |= 1u << best; ssum += bv;
      }
      const float inv = 1.f / (ssum + 1e-6f);
#pragma unroll
      for (int e = 0; e < 16; ++e) wv[e] = ((um >> e) & 1u) ? p[e] * inv : 0.f;
    }
#pragma unroll
    for (int e = 0; e < 16; ++e) wexp[tt * 16 + e] = wv[e];
  }
  __syncthreads();

#pragma unroll
  for (int it = 0; it < 16; ++it) {
    int idx = tid + it * 256;
    int tt = idx >> 7, c8 = idx & 127;
    int n = c8 >> 3, r0 = (c8 & 7) * 8;
    const float wv = wexp[tt * 16 + n];
    const float* hb = &arr[tt * 80 + 16 + r0];
    ushort4 lo, hi;
    lo.x = bfbits(wv * hb[0]); lo.y = bfbits(wv * hb[1]);
    lo.z = bfbits(wv * hb[2]); lo.w = bfbits(wv * hb[3]);
    hi.x = bfbits(wv * hb[4]); hi.y = bfbits(wv * hb[5]);
    hi.z = bfbits(wv * hb[6]); hi.w = bfbits(wv * hb[7]);
    u16* dst = Xa + (size_t)(token0 + tt) * K_TOT + K_IN + c8 * 8;
    *(ushort4*)(dst) = lo;
    *(ushort4*)(dst + 4) = hi;
  }
}

// ------ Kernel 3 (r8, frozen): 256^2 GEMM, ONE barrier per phase ------
#define PHASE_BAR() do {                      \
  __builtin_amdgcn_sched_barrier(0);          \
  __builtin_amdgcn_s_barrier();               \
  __builtin_amdgcn_sched_barrier(0);          \
} while (0)

#define LGKM0() do {                          \
  asm volatile("s_waitcnt lgkmcnt(0)");       \
  __builtin_amdgcn_sched_barrier(0);          \
} while (0)

__global__ __launch_bounds__(512, 2) void gemm_aug(const u16* __restrict__ Xa,
                                                   const u16* __restrict__ Wa,
                                                   const float* __restrict__ bias,
                                                   float* __restrict__ out) {
  extern __shared__ u16 lds[];
  const int tid = threadIdx.x;
  const int w = tid >> 6, l = tid & 63;
  const int bid = blockIdx.x;
  const int wg = (bid & 7) * 64 + (bid >> 3);     // T1: XCD-bijective (512%8==0)
  const int bm = wg >> 4, bn = wg & 15;
  const int wm = w >> 2, wn = w & 3;

  const int srow = w * 8 + (l >> 3);
  const int gsw = ((l & 7) ^ (l >> 3)) * 8;       // pre-swizzled global granule
  const u16* sA = Xa + (size_t)(bm * 256 + srow) * K_TOT + gsw;
  const u16* sB = Wa + (size_t)(bn * 256 + srow) * K_TOT + gsw;
  const int stq = w * 512;

  const int arow = (l & 15) * 64;
  const int c0 = (((l >> 4) + 0) ^ (l & 7)) * 8;
  const int c1 = (((l >> 4) + 4) ^ (l & 7)) * 8;

  f32x4 acc[8][4] = {};

#define STAGE_A2(tile, half, bufc) do {                                        \
    const u16* s_ = sA + (size_t)(half) * 128 * K_TOT + (size_t)(tile) * 64;   \
    const int d_ = (bufc) * 32768 + (half) * 8192 + stq;                       \
    gload_lds16(s_, &lds[d_]);                                                 \
    gload_lds16(s_ + (size_t)64 * K_TOT, &lds[d_ + 4096]);                     \
  } while (0)
#define STAGE_B2(tile, half, bufc) do {                                        \
    const u16* s_ = sB + (size_t)(half) * 128 * K_TOT + (size_t)(tile) * 64;   \
    const int d_ = (bufc) * 32768 + 16384 + (half) * 8192 + stq;               \
    gload_lds16(s_, &lds[d_]);                                                 \
    gload_lds16(s_ + (size_t)64 * K_TOT, &lds[d_ + 4096]);                     \
  } while (0)

  // prologue: tile0 full + tile1 {B0,B1,A0}; wait tile0 landed (vmcnt(6))
  STAGE_B2(0, 0, 0); STAGE_B2(0, 1, 0); STAGE_A2(0, 0, 0); STAGE_A2(0, 1, 0);
  STAGE_B2(1, 0, 1); STAGE_B2(1, 1, 1); STAGE_A2(1, 0, 1);
  __builtin_amdgcn_sched_barrier(0);
  asm volatile("s_waitcnt vmcnt(6)");
  PHASE_BAR();

#define DO_TILE(TT, BUFC) do {                                                 \
    const int aoff_ = (BUFC) * 32768 + wm * 8192;                              \
    const int boff_ = (BUFC) * 32768 + 16384 + (wn >> 1) * 8192 + (wn & 1) * 4096; \
    bf16x8 af[4][2], b0f[2][2], b1f[2][2];                                     \
    /* P1: reads af-mh0 (8) + b0f (4); stage A1(t+1)->buf^1; BAR; MFMA (0,0) */ \
    _Pragma("unroll")                                                          \
    for (int m = 0; m < 4; ++m) {                                              \
      af[m][0] = *(const bf16x8*)&lds[aoff_ + m * 1024 + arow + c0];           \
      af[m][1] = *(const bf16x8*)&lds[aoff_ + m * 1024 + arow + c1];           \
    }                                                                          \
    _Pragma("unroll")                                                          \
    for (int n = 0; n < 2; ++n) {                                              \
      b0f[n][0] = *(const bf16x8*)&lds[boff_ + n * 1024 + arow + c0];          \
      b0f[n][1] = *(const bf16x8*)&lds[boff_ + n * 1024 + arow + c1];          \
    }                                                                          \
    if ((TT) + 1 < NT) STAGE_A2((TT) + 1, 1, (BUFC) ^ 1);                      \
    PHASE_BAR(); LGKM0();                                                      \
    __builtin_amdgcn_s_setprio(1);                                             \
    _Pragma("unroll")                                                          \
    for (int m = 0; m < 4; ++m)                                                \
      _Pragma("unroll")                                                        \
      for (int n = 0; n < 2; ++n) {                                            \
        acc[m][n] = MFMA16(af[m][0], b0f[n][0], acc[m][n], 0, 0, 0);           \
        acc[m][n] = MFMA16(af[m][1], b0f[n][1], acc[m][n], 0, 0, 0);           \
      }                                                                        \
    __builtin_amdgcn_s_setprio(0);                                             \
    /* P2: reads b1f (4); no stage; BAR; MFMA (0,1) */                         \
    _Pragma("unroll")                                                          \
    for (int n = 0; n < 2; ++n) {                                              \
      b1f[n][0] = *(const bf16x8*)&lds[boff_ + (n + 2) * 1024 + arow + c0];    \
      b1f[n][1] = *(const bf16x8*)&lds[boff_ + (n + 2) * 1024 + arow + c1];    \
    }                                                                          \
    PHASE_BAR(); LGKM0();                                                      \
    __builtin_amdgcn_s_setprio(1);                                             \
    _Pragma("unroll")                                                          \
    for (int m = 0; m < 4; ++m)                                                \
      _Pragma("unroll")                                                        \
      for (int n = 0; n < 2; ++n) {                                            \
        acc[m][n + 2] = MFMA16(af[m][0], b1f[n][0], acc[m][n + 2], 0, 0, 0);   \
        acc[m][n + 2] = MFMA16(af[m][1], b1f[n][1], acc[m][n + 2], 0, 0, 0);   \
      }                                                                        \
    __builtin_amdgcn_s_setprio(0);                                             \
    /* P3: reads af-mh1 (8); stage B0(t+2); BAR; MFMA (1,1) */                 \
    _Pragma("unroll")                                                          \
    for (int m = 0; m < 4; ++m) {                                              \
      af[m][0] = *(const bf16x8*)&lds[aoff_ + 4096 + m * 1024 + arow + c0];    \
      af[m][1] = *(const bf16x8*)&lds[aoff_ + 4096 + m * 1024 + arow + c1];    \
    }                                                                          \
    if ((TT) + 2 < NT) STAGE_B2((TT) + 2, 0, (BUFC));                          \
    PHASE_BAR(); LGKM0();                                                      \
    __builtin_amdgcn_s_setprio(1);                                             \
    _Pragma("unroll")                                                          \
    for (int m = 0; m < 4; ++m)                                                \
      _Pragma("unroll")                                                        \
      for (int n = 0; n < 2; ++n) {                                            \
        acc[m + 4][n + 2] = MFMA16(af[m][0], b1f[n][0], acc[m + 4][n + 2], 0, 0, 0); \
        acc[m + 4][n + 2] = MFMA16(af[m][1], b1f[n][1], acc[m + 4][n + 2], 0, 0, 0); \
      }                                                                        \
    __builtin_amdgcn_s_setprio(0);                                             \
    /* P4: no reads; stage B1(t+2)+A0(t+2); vmcnt(6); BAR; MFMA (1,0) */       \
    if ((TT) + 2 < NT) {                                                       \
      STAGE_B2((TT) + 2, 1, (BUFC));                                           \
      STAGE_A2((TT) + 2, 0, (BUFC));                                           \
      __builtin_amdgcn_sched_barrier(0);                                       \
      asm volatile("s_waitcnt vmcnt(6)");                                      \
    } else {                                                                   \
      asm volatile("s_waitcnt vmcnt(0)");                                      \
    }                                                                          \
    PHASE_BAR();                                                               \
    __builtin_amdgcn_s_setprio(1);                                             \
    _Pragma("unroll")                                                          \
    for (int m = 0; m < 4; ++m)                                                \
      _Pragma("unroll")                                                        \
      for (int n = 0; n < 2; ++n) {                                            \
        acc[m + 4][n] = MFMA16(af[m][0], b0f[n][0], acc[m + 4][n], 0, 0, 0);   \
        acc[m + 4][n] = MFMA16(af[m][1], b0f[n][1], acc[m + 4][n], 0, 0, 0);   \
      }                                                                        \
    __builtin_amdgcn_s_setprio(0);                                             \
  } while (0)

  for (int t = 0; t < NT; t += 2) {
    DO_TILE(t, 0);
    DO_TILE(t + 1, 1);
  }

  // ---- epilogue: C/D layout col=lane&15, row=(lane>>4)*4+reg ----
  const int colBase = bn * 256 + wn * 64 + (l & 15);
  float bv[4];
#pragma unroll
  for (int n = 0; n < 4; ++n) bv[n] = bias[colBase + n * 16];
#pragma unroll
  for (int mi = 0; mi < 8; ++mi) {
    const int row = bm * 256 + wm * 128 + mi * 16 + (l >> 4) * 4;
#pragma unroll
    for (int j = 0; j < 4; ++j) {
      float* orow = out + (size_t)(row + j) * N_OUT + colBase;
#pragma unroll
      for (int n = 0; n < 4; ++n) orow[n * 16] = acc[mi][n][j] + bv[n];
    }
  }
}

extern "C" void kernel_launch(void* const* d_in, const int* in_sizes, int n_in,
                              void* d_out, int out_size, void* d_ws, size_t ws_size,
                              hipStream_t stream) {
  const float* x  = (const float*)d_in[0];
  const float* Wb = (const float*)d_in[1];
  const float* bb = (const float*)d_in[2];
  const float* Am = (const float*)d_in[3];
  const float* Bm = (const float*)d_in[4];
  const float* Wr = (const float*)d_in[5];
  const int* topk = (const int*)d_in[6];
  float* out = (float*)d_out;

  u16* Xa  = (u16*)d_ws;                          // 8192*5120 bf16
  u16* Wa  = Xa + (size_t)M_TOT * K_TOT;          // 4096*5120 bf16
  u16* Msp = Wa + (size_t)N_OUT * K_TOT;          // 64*96*64 bf16 (786 KB)

  (void)hipFuncSetAttribute((const void*)gemm_aug,
                            hipFuncAttributeMaxDynamicSharedMemorySize, 131072);

  hipLaunchKernelGGL(build_msp,  dim3(96),         dim3(256), 0, stream,
                     Wr, Am, Msp);
  hipLaunchKernelGGL(prep_fused, dim3(256 + N_OUT), dim3(256), 0, stream,
                     x, Msp, topk, Wb, Bm, Xa, Wa);
  hipLaunchKernelGGL(gemm_aug,   dim3(512),        dim3(512), 131072, stream,
                     Xa, Wa, bb, out);
}